// Round 1
// baseline (268.151 us; speedup 1.0000x reference)
//
#include <hip/hip_runtime.h>

// SelfAttention fused pipeline, bf16 MFMA path.
// x[4,512,48,48] -> GN(32 groups) -> qkv 1x1 conv -> 8-head attn (N=2304,D=64) -> out proj.
// ws layout (needs ~68.2 MB):
//   xnT   [4][2304][512] bf16   @ 0
//   qkv   [4][1536][2304] bf16  @ 9437184      (q rows 0-511, k 512-1023, v 1024-1535; d-major)
//   qT    [4][8][2304][64] bf16 @ 37748736     (pre-scaled by 0.125)
//   kT    [4][8][2304][64] bf16 @ 47185920
//   innerT[4][2304][512] bf16   @ 56623104
//   wq_bf [1536][512] bf16      @ 66060288
//   wo_bf [512][512]  bf16      @ 67633152
//   stats [4][32] float2        @ 68157440

typedef unsigned short u16;
typedef __attribute__((ext_vector_type(8))) short bf16x8;
typedef __attribute__((ext_vector_type(4))) float f32x4;
typedef __attribute__((ext_vector_type(8))) unsigned short us8;
typedef __attribute__((ext_vector_type(4))) unsigned short us4;

#define B_ 4
#define C_ 512
#define N_ 2304
#define H_ 8
#define D_ 64
#define G_ 32

__device__ __forceinline__ u16 f2bf(float f) {
  unsigned u = __float_as_uint(f);
  u += 0x7FFFu + ((u >> 16) & 1u);   // RNE
  return (u16)(u >> 16);
}
__device__ __forceinline__ float bf2f(u16 h) {
  return __uint_as_float(((unsigned)h) << 16);
}

// ---------------- weight cast ----------------
__global__ __launch_bounds__(256) void cast_weights(
    const float* __restrict__ wq, const float* __restrict__ wo,
    u16* __restrict__ wq_bf, u16* __restrict__ wo_bf) {
  const int n1 = 1536 * 512 / 4, n2 = 512 * 512 / 4;
  for (int i = blockIdx.x * 256 + threadIdx.x; i < n1 + n2; i += gridDim.x * 256) {
    const float4 v = (i < n1) ? ((const float4*)wq)[i] : ((const float4*)wo)[i - n1];
    us4 o; o[0] = f2bf(v.x); o[1] = f2bf(v.y); o[2] = f2bf(v.z); o[3] = f2bf(v.w);
    if (i < n1) ((us4*)wq_bf)[i] = o; else ((us4*)wo_bf)[i - n1] = o;
  }
}

// ---------------- groupnorm stats: one block per (b,g) ----------------
__global__ __launch_bounds__(256) void gn_stats(const float* __restrict__ x,
                                                float2* __restrict__ stats) {
  const int bg = blockIdx.x;                      // b*32+g
  const float* p = x + (size_t)bg * 16 * N_;      // group is contiguous
  float s = 0.f, s2 = 0.f;
  for (int i = threadIdx.x; i < 16 * N_ / 4; i += 256) {
    const float4 v = ((const float4*)p)[i];
    s  += v.x + v.y + v.z + v.w;
    s2 += v.x * v.x + v.y * v.y + v.z * v.z + v.w * v.w;
  }
  #pragma unroll
  for (int off = 32; off; off >>= 1) { s += __shfl_down(s, off); s2 += __shfl_down(s2, off); }
  __shared__ float red[8];
  if ((threadIdx.x & 63) == 0) { red[(threadIdx.x >> 6) * 2] = s; red[(threadIdx.x >> 6) * 2 + 1] = s2; }
  __syncthreads();
  if (threadIdx.x == 0) {
    float S = 0.f, S2 = 0.f;
    for (int w = 0; w < 4; w++) { S += red[w * 2]; S2 += red[w * 2 + 1]; }
    const float inv = 1.f / (16.f * N_);
    const float mean = S * inv;
    const float var = S2 * inv - mean * mean;
    stats[bg] = make_float2(mean, rsqrtf(var + 1e-5f));
  }
}

// ---------------- GN apply + transpose -> xnT[b][n][c] bf16 ----------------
__global__ __launch_bounds__(256) void gn_apply_t(
    const float* __restrict__ x, const float2* __restrict__ stats,
    const float* __restrict__ gamma, const float* __restrict__ beta,
    u16* __restrict__ xnT) {
  __shared__ u16 T[64][72];
  const int c0 = blockIdx.x * 64, n0 = blockIdx.y * 64, b = blockIdx.z;
  const int r = threadIdx.x >> 2, ch = (threadIdx.x & 3) * 16;
  const int cc = c0 + r;
  const float2 st = stats[b * G_ + (cc >> 4)];
  const float sc = st.y * gamma[cc];
  const float sh = beta[cc] - st.x * sc;
  const float* src = x + (size_t)(b * C_ + cc) * N_ + n0 + ch;
  #pragma unroll
  for (int j = 0; j < 16; j += 4) {
    const float4 v = *(const float4*)(src + j);
    us4 o; o[0] = f2bf(v.x * sc + sh); o[1] = f2bf(v.y * sc + sh);
    o[2] = f2bf(v.z * sc + sh); o[3] = f2bf(v.w * sc + sh);
    *(us4*)&T[r][ch + j] = o;
  }
  __syncthreads();
  us8 o1, o2;
  #pragma unroll
  for (int j = 0; j < 8; j++) { o1[j] = T[ch + j][r]; o2[j] = T[ch + 8 + j][r]; }
  u16* dst = xnT + (size_t)(b * N_ + n0 + r) * C_ + c0 + ch;
  *(us8*)dst = o1;
  *(us8*)(dst + 8) = o2;
}

// ---------------- GEMM: C[bz][m][n] = A[m][k] * B[bz][n][k]^T ----------------
// A: weights bf16 [M][K]; B: activations bf16 [batch][N][K] (K contiguous).
template <bool OUT_F32_BIAS>
__global__ __launch_bounds__(256) void gemm_bf16(
    const u16* __restrict__ A, const u16* __restrict__ B,
    void* __restrict__ C, const float* __restrict__ bias,
    const int M, const int N, const int K) {
  __shared__ u16 As[128][40];
  __shared__ u16 Bs[128][40];
  const int tid = threadIdx.x;
  const int wave = tid >> 6, lane = tid & 63;
  const int l16 = lane & 15, lq = lane >> 4;
  const int m0 = blockIdx.x * 128, n0 = blockIdx.y * 128, bz = blockIdx.z;
  const int wm = (wave >> 1) * 64, wn = (wave & 1) * 64;
  const u16* Bb = B + (size_t)bz * N * K;

  f32x4 acc[4][4];
  #pragma unroll
  for (int mi = 0; mi < 4; mi++)
    #pragma unroll
    for (int ni = 0; ni < 4; ni++) {
      acc[mi][ni][0] = 0.f; acc[mi][ni][1] = 0.f; acc[mi][ni][2] = 0.f; acc[mi][ni][3] = 0.f;
    }

  const int r = tid >> 2, c = (tid & 3) * 8;
  for (int kt = 0; kt < K; kt += 32) {
    __syncthreads();
    *(us8*)&As[r][c]      = *(const us8*)&A[(size_t)(m0 + r) * K + kt + c];
    *(us8*)&As[r + 64][c] = *(const us8*)&A[(size_t)(m0 + r + 64) * K + kt + c];
    *(us8*)&Bs[r][c]      = *(const us8*)&Bb[(size_t)(n0 + r) * K + kt + c];
    *(us8*)&Bs[r + 64][c] = *(const us8*)&Bb[(size_t)(n0 + r + 64) * K + kt + c];
    __syncthreads();
    bf16x8 af[4], bfr[4];
    #pragma unroll
    for (int mi = 0; mi < 4; mi++) af[mi] = *(const bf16x8*)&As[wm + mi * 16 + l16][lq * 8];
    #pragma unroll
    for (int ni = 0; ni < 4; ni++) bfr[ni] = *(const bf16x8*)&Bs[wn + ni * 16 + l16][lq * 8];
    #pragma unroll
    for (int mi = 0; mi < 4; mi++)
      #pragma unroll
      for (int ni = 0; ni < 4; ni++)
        acc[mi][ni] = __builtin_amdgcn_mfma_f32_16x16x32_bf16(af[mi], bfr[ni], acc[mi][ni], 0, 0, 0);
  }
  #pragma unroll
  for (int mi = 0; mi < 4; mi++) {
    const int row0 = m0 + wm + mi * 16 + lq * 4;
    #pragma unroll
    for (int ni = 0; ni < 4; ni++) {
      const int col = n0 + wn + ni * 16 + l16;
      #pragma unroll
      for (int j = 0; j < 4; j++) {
        const size_t idx = ((size_t)bz * M + row0 + j) * N + col;
        if (OUT_F32_BIAS) ((float*)C)[idx] = acc[mi][ni][j] + bias[row0 + j];
        else              ((u16*)C)[idx] = f2bf(acc[mi][ni][j]);
      }
    }
  }
}

// ---------------- transpose q,k sections -> [b][h][n][d]; q scaled by 0.125 ----------------
__global__ __launch_bounds__(256) void qk_transpose(
    const u16* __restrict__ qkv, u16* __restrict__ qT, u16* __restrict__ kT) {
  __shared__ u16 T[64][72];
  const int wh = blockIdx.x;            // which*8 + h
  const int which = wh >> 3, h = wh & 7;
  const int n0 = blockIdx.y * 64, b = blockIdx.z;
  const int r = threadIdx.x >> 2, ch = (threadIdx.x & 3) * 16;
  const u16* src = qkv + (size_t)(b * 3 * C_ + which * C_ + h * D_ + r) * N_ + n0 + ch;
  us8 v1 = *(const us8*)src;
  us8 v2 = *(const us8*)(src + 8);
  if (which == 0) {  // q * 0.125 (power of 2 -> exact in bf16)
    #pragma unroll
    for (int j = 0; j < 8; j++) { v1[j] = f2bf(bf2f(v1[j]) * 0.125f); v2[j] = f2bf(bf2f(v2[j]) * 0.125f); }
  }
  *(us8*)&T[r][ch] = v1;
  *(us8*)&T[r][ch + 8] = v2;
  __syncthreads();
  us8 o1, o2;
  #pragma unroll
  for (int j = 0; j < 8; j++) { o1[j] = T[ch + j][r]; o2[j] = T[ch + 8 + j][r]; }
  u16* dst = (which ? kT : qT) + (size_t)((b * H_ + h) * N_ + n0 + r) * D_ + ch;
  *(us8*)dst = o1;
  *(us8*)(dst + 8) = o2;
}

// ---------------- flash attention: block = (h, q-tile of 64, b), 4 waves ----------------
__global__ __launch_bounds__(256) void attn_kernel(
    const u16* __restrict__ qT, const u16* __restrict__ kT,
    const u16* __restrict__ qkv, u16* __restrict__ innerT) {
  __shared__ u16 Qs[64][72];
  __shared__ u16 Ks[64][72];
  __shared__ u16 Vs[64][72];
  __shared__ u16 Ps[4][16][72];

  const int h = blockIdx.x, b = blockIdx.z;
  const int q0 = blockIdx.y * 64;
  const int tid = threadIdx.x;
  const int wave = tid >> 6, lane = tid & 63;
  const int l16 = lane & 15, lq = lane >> 4;

  {
    const int r = tid >> 2, ch = (tid & 3) * 16;
    const u16* src = qT + ((size_t)((b * H_ + h) * N_ + q0 + r)) * D_ + ch;
    *(us8*)&Qs[r][ch] = *(const us8*)src;
    *(us8*)&Qs[r][ch + 8] = *(const us8*)(src + 8);
  }

  float m_run[4], l_run[4];
  f32x4 acc[4];
  #pragma unroll
  for (int j = 0; j < 4; j++) {
    m_run[j] = -1e30f; l_run[j] = 0.f;
    acc[j][0] = 0.f; acc[j][1] = 0.f; acc[j][2] = 0.f; acc[j][3] = 0.f;
  }

  const u16* kbase = kT + (size_t)(b * H_ + h) * N_ * D_;
  const u16* vbase = qkv + ((size_t)(b * 3 * C_) + 2 * C_ + h * D_) * N_;

  for (int kt = 0; kt < N_ / 64; kt++) {
    __syncthreads();
    {
      const int r = tid >> 2, ch = (tid & 3) * 16;
      const u16* ks = kbase + ((size_t)(kt * 64 + r)) * D_ + ch;
      *(us8*)&Ks[r][ch] = *(const us8*)ks;
      *(us8*)&Ks[r][ch + 8] = *(const us8*)(ks + 8);
      const u16* vs = vbase + (size_t)r * N_ + kt * 64 + ch;
      *(us8*)&Vs[r][ch] = *(const us8*)vs;
      *(us8*)&Vs[r][ch + 8] = *(const us8*)(vs + 8);
    }
    __syncthreads();

    // S = Q K^T (scale folded into qT)
    const bf16x8 aq0 = *(const bf16x8*)&Qs[wave * 16 + l16][lq * 8];
    const bf16x8 aq1 = *(const bf16x8*)&Qs[wave * 16 + l16][32 + lq * 8];
    f32x4 s[4];
    #pragma unroll
    for (int ni = 0; ni < 4; ni++) {
      s[ni][0] = 0.f; s[ni][1] = 0.f; s[ni][2] = 0.f; s[ni][3] = 0.f;
      const bf16x8 b0 = *(const bf16x8*)&Ks[ni * 16 + l16][lq * 8];
      const bf16x8 b1 = *(const bf16x8*)&Ks[ni * 16 + l16][32 + lq * 8];
      s[ni] = __builtin_amdgcn_mfma_f32_16x16x32_bf16(aq0, b0, s[ni], 0, 0, 0);
      s[ni] = __builtin_amdgcn_mfma_f32_16x16x32_bf16(aq1, b1, s[ni], 0, 0, 0);
    }

    // online softmax (rows live on 16-lane groups; j indexes 4 rows per lane)
    float mt[4];
    #pragma unroll
    for (int j = 0; j < 4; j++)
      mt[j] = fmaxf(fmaxf(s[0][j], s[1][j]), fmaxf(s[2][j], s[3][j]));
    #pragma unroll
    for (int msk = 1; msk < 16; msk <<= 1) {
      #pragma unroll
      for (int j = 0; j < 4; j++) mt[j] = fmaxf(mt[j], __shfl_xor(mt[j], msk));
    }
    float alpha[4], rs[4];
    #pragma unroll
    for (int j = 0; j < 4; j++) {
      const float mn = fmaxf(m_run[j], mt[j]);
      alpha[j] = __expf(m_run[j] - mn);
      m_run[j] = mn;
      rs[j] = 0.f;
    }
    #pragma unroll
    for (int ni = 0; ni < 4; ni++)
      #pragma unroll
      for (int j = 0; j < 4; j++) {
        const float p = __expf(s[ni][j] - m_run[j]);
        s[ni][j] = p;
        rs[j] += p;
      }
    #pragma unroll
    for (int msk = 1; msk < 16; msk <<= 1) {
      #pragma unroll
      for (int j = 0; j < 4; j++) rs[j] += __shfl_xor(rs[j], msk);
    }
    #pragma unroll
    for (int j = 0; j < 4; j++) l_run[j] = l_run[j] * alpha[j] + rs[j];
    #pragma unroll
    for (int di = 0; di < 4; di++)
      #pragma unroll
      for (int j = 0; j < 4; j++) acc[di][j] *= alpha[j];

    // P (D-layout) -> per-wave LDS -> A-layout
    #pragma unroll
    for (int ni = 0; ni < 4; ni++)
      #pragma unroll
      for (int j = 0; j < 4; j++)
        Ps[wave][lq * 4 + j][ni * 16 + l16] = f2bf(s[ni][j]);

    const bf16x8 ap0 = *(const bf16x8*)&Ps[wave][l16][lq * 8];
    const bf16x8 ap1 = *(const bf16x8*)&Ps[wave][l16][32 + lq * 8];
    #pragma unroll
    for (int di = 0; di < 4; di++) {
      const bf16x8 v0 = *(const bf16x8*)&Vs[di * 16 + l16][lq * 8];
      const bf16x8 v1 = *(const bf16x8*)&Vs[di * 16 + l16][32 + lq * 8];
      acc[di] = __builtin_amdgcn_mfma_f32_16x16x32_bf16(ap0, v0, acc[di], 0, 0, 0);
      acc[di] = __builtin_amdgcn_mfma_f32_16x16x32_bf16(ap1, v1, acc[di], 0, 0, 0);
    }
  }

  #pragma unroll
  for (int di = 0; di < 4; di++) {
    #pragma unroll
    for (int j = 0; j < 4; j++) {
      const int n = q0 + wave * 16 + lq * 4 + j;
      const int d = di * 16 + l16;
      innerT[(size_t)(b * N_ + n) * (H_ * D_) + h * D_ + d] = f2bf(acc[di][j] / l_run[j]);
    }
  }
}

extern "C" void kernel_launch(void* const* d_in, const int* in_sizes, int n_in,
                              void* d_out, int out_size, void* d_ws, size_t ws_size,
                              hipStream_t stream) {
  const float* x     = (const float*)d_in[0];
  const float* gamma = (const float*)d_in[1];
  const float* beta  = (const float*)d_in[2];
  const float* w_qkv = (const float*)d_in[3];
  const float* w_out = (const float*)d_in[4];
  const float* b_out = (const float*)d_in[5];
  float* out = (float*)d_out;

  char* ws = (char*)d_ws;
  u16*    xnT    = (u16*)(ws + 0);
  u16*    qkv    = (u16*)(ws + 9437184);
  u16*    qT     = (u16*)(ws + 37748736);
  u16*    kT     = (u16*)(ws + 47185920);
  u16*    innerT = (u16*)(ws + 56623104);
  u16*    wq_bf  = (u16*)(ws + 66060288);
  u16*    wo_bf  = (u16*)(ws + 67633152);
  float2* stats  = (float2*)(ws + 68157440);

  cast_weights<<<dim3(256), dim3(256), 0, stream>>>(w_qkv, w_out, wq_bf, wo_bf);
  gn_stats<<<dim3(B_ * G_), dim3(256), 0, stream>>>(x, stats);
  gn_apply_t<<<dim3(C_ / 64, N_ / 64, B_), dim3(256), 0, stream>>>(x, stats, gamma, beta, xnT);
  gemm_bf16<false><<<dim3(12, 18, B_), dim3(256), 0, stream>>>(wq_bf, xnT, (void*)qkv, nullptr, 1536, N_, C_);
  qk_transpose<<<dim3(16, N_ / 64, B_), dim3(256), 0, stream>>>(qkv, qT, kT);
  attn_kernel<<<dim3(H_, N_ / 64, B_), dim3(256), 0, stream>>>(qT, kT, qkv, innerT);
  gemm_bf16<true><<<dim3(4, 18, B_), dim3(256), 0, stream>>>(wo_bf, innerT, (void*)out, b_out, C_, N_, C_);
}

// Round 2
// 198.442 us; speedup vs baseline: 1.3513x; 1.3513x over previous
//
#include <hip/hip_runtime.h>
#include <hip/hip_bf16.h>

// SelfAttention fused pipeline, bf16 MFMA path.
// x[4,512,48,48] -> GN(32 groups) -> qkv 1x1 conv -> 8-head attn (N=2304,D=64) -> out proj.
// ws layout:
//   xnT   [4][2304][512] bf16   @ 0
//   qkv   [4][1536][2304] bf16  @ 9437184      (q rows 0-511, k 512-1023, v 1024-1535; d-major)
//   qT    [4][8][2304][64] bf16 @ 37748736     (pre-scaled by log2(e)/8, folded into W_q)
//   kT    [4][8][2304][64] bf16 @ 47185920
//   innerT[4][2304][512] bf16   @ 56623104
//   wq_bf [1536][512] bf16      @ 66060288
//   wo_bf [512][512]  bf16      @ 67633152
//   stats [4][32] float2        @ 68157440

typedef unsigned short u16;
typedef unsigned int u32;
typedef __attribute__((ext_vector_type(8))) short bf16x8;
typedef __attribute__((ext_vector_type(4))) float f32x4;
typedef __attribute__((ext_vector_type(8))) unsigned short us8;
typedef __attribute__((ext_vector_type(4))) unsigned short us4;

#define B_ 4
#define C_ 512
#define N_ 2304
#define H_ 8
#define D_ 64
#define G_ 32

// log2(e)/8: folded into W_q so QK^T lands directly in exp2 domain.
#define QSCALE 0.1803368801111204f

__device__ __forceinline__ u16 f2bf(float f) {
  unsigned u = __float_as_uint(f);
  u += 0x7FFFu + ((u >> 16) & 1u);   // RNE
  return (u16)(u >> 16);
}

__device__ __forceinline__ u32 pack2bf(float lo, float hi) {
  __hip_bfloat162 t = __float22bfloat162_rn(float2{lo, hi});
  u32 r;
  __builtin_memcpy(&r, &t, 4);
  return r;
}

// ---------------- weight cast (q rows pre-scaled) ----------------
__global__ __launch_bounds__(256) void cast_weights(
    const float* __restrict__ wq, const float* __restrict__ wo,
    u16* __restrict__ wq_bf, u16* __restrict__ wo_bf) {
  const int n1 = 1536 * 512 / 4, n2 = 512 * 512 / 4;
  const int nq = 512 * 512 / 4;   // q section in float4 units
  for (int i = blockIdx.x * 256 + threadIdx.x; i < n1 + n2; i += gridDim.x * 256) {
    const float4 v = (i < n1) ? ((const float4*)wq)[i] : ((const float4*)wo)[i - n1];
    const float sc = (i < nq) ? QSCALE : 1.0f;
    us4 o; o[0] = f2bf(v.x * sc); o[1] = f2bf(v.y * sc); o[2] = f2bf(v.z * sc); o[3] = f2bf(v.w * sc);
    if (i < n1) ((us4*)wq_bf)[i] = o; else ((us4*)wo_bf)[i - n1] = o;
  }
}

// ---------------- groupnorm stats: one block per (b,g) ----------------
__global__ __launch_bounds__(256) void gn_stats(const float* __restrict__ x,
                                                float2* __restrict__ stats) {
  const int bg = blockIdx.x;
  const float* p = x + (size_t)bg * 16 * N_;
  float s = 0.f, s2 = 0.f;
  for (int i = threadIdx.x; i < 16 * N_ / 4; i += 256) {
    const float4 v = ((const float4*)p)[i];
    s  += v.x + v.y + v.z + v.w;
    s2 += v.x * v.x + v.y * v.y + v.z * v.z + v.w * v.w;
  }
  #pragma unroll
  for (int off = 32; off; off >>= 1) { s += __shfl_down(s, off); s2 += __shfl_down(s2, off); }
  __shared__ float red[8];
  if ((threadIdx.x & 63) == 0) { red[(threadIdx.x >> 6) * 2] = s; red[(threadIdx.x >> 6) * 2 + 1] = s2; }
  __syncthreads();
  if (threadIdx.x == 0) {
    float S = 0.f, S2 = 0.f;
    for (int w = 0; w < 4; w++) { S += red[w * 2]; S2 += red[w * 2 + 1]; }
    const float inv = 1.f / (16.f * N_);
    const float mean = S * inv;
    const float var = S2 * inv - mean * mean;
    stats[bg] = make_float2(mean, rsqrtf(var + 1e-5f));
  }
}

// ---------------- GN apply + transpose -> xnT[b][n][c] bf16 ----------------
__global__ __launch_bounds__(256) void gn_apply_t(
    const float* __restrict__ x, const float2* __restrict__ stats,
    const float* __restrict__ gamma, const float* __restrict__ beta,
    u16* __restrict__ xnT) {
  __shared__ u16 T[64][72];
  const int c0 = blockIdx.x * 64, n0 = blockIdx.y * 64, b = blockIdx.z;
  const int r = threadIdx.x >> 2, ch = (threadIdx.x & 3) * 16;
  const int cc = c0 + r;
  const float2 st = stats[b * G_ + (cc >> 4)];
  const float sc = st.y * gamma[cc];
  const float sh = beta[cc] - st.x * sc;
  const float* src = x + (size_t)(b * C_ + cc) * N_ + n0 + ch;
  #pragma unroll
  for (int j = 0; j < 16; j += 4) {
    const float4 v = *(const float4*)(src + j);
    us4 o; o[0] = f2bf(v.x * sc + sh); o[1] = f2bf(v.y * sc + sh);
    o[2] = f2bf(v.z * sc + sh); o[3] = f2bf(v.w * sc + sh);
    *(us4*)&T[r][ch + j] = o;
  }
  __syncthreads();
  us8 o1, o2;
  #pragma unroll
  for (int j = 0; j < 8; j++) { o1[j] = T[ch + j][r]; o2[j] = T[ch + 8 + j][r]; }
  u16* dst = xnT + (size_t)(b * N_ + n0 + r) * C_ + c0 + ch;
  *(us8*)dst = o1;
  *(us8*)(dst + 8) = o2;
}

// ---------------- GEMM: C[bz][m][n] = A[m][k] * B[bz][n][k]^T ----------------
template <bool OUT_F32_BIAS>
__global__ __launch_bounds__(256) void gemm_bf16(
    const u16* __restrict__ A, const u16* __restrict__ B,
    void* __restrict__ C, const float* __restrict__ bias,
    const int M, const int N, const int K) {
  __shared__ u16 As[128][40];
  __shared__ u16 Bs[128][40];
  const int tid = threadIdx.x;
  const int wave = tid >> 6, lane = tid & 63;
  const int l16 = lane & 15, lq = lane >> 4;
  const int m0 = blockIdx.x * 128, n0 = blockIdx.y * 128, bz = blockIdx.z;
  const int wm = (wave >> 1) * 64, wn = (wave & 1) * 64;
  const u16* Bb = B + (size_t)bz * N * K;

  f32x4 acc[4][4];
  #pragma unroll
  for (int mi = 0; mi < 4; mi++)
    #pragma unroll
    for (int ni = 0; ni < 4; ni++) {
      acc[mi][ni][0] = 0.f; acc[mi][ni][1] = 0.f; acc[mi][ni][2] = 0.f; acc[mi][ni][3] = 0.f;
    }

  const int r = tid >> 2, c = (tid & 3) * 8;
  for (int kt = 0; kt < K; kt += 32) {
    __syncthreads();
    *(us8*)&As[r][c]      = *(const us8*)&A[(size_t)(m0 + r) * K + kt + c];
    *(us8*)&As[r + 64][c] = *(const us8*)&A[(size_t)(m0 + r + 64) * K + kt + c];
    *(us8*)&Bs[r][c]      = *(const us8*)&Bb[(size_t)(n0 + r) * K + kt + c];
    *(us8*)&Bs[r + 64][c] = *(const us8*)&Bb[(size_t)(n0 + r + 64) * K + kt + c];
    __syncthreads();
    bf16x8 af[4], bfr[4];
    #pragma unroll
    for (int mi = 0; mi < 4; mi++) af[mi] = *(const bf16x8*)&As[wm + mi * 16 + l16][lq * 8];
    #pragma unroll
    for (int ni = 0; ni < 4; ni++) bfr[ni] = *(const bf16x8*)&Bs[wn + ni * 16 + l16][lq * 8];
    #pragma unroll
    for (int mi = 0; mi < 4; mi++)
      #pragma unroll
      for (int ni = 0; ni < 4; ni++)
        acc[mi][ni] = __builtin_amdgcn_mfma_f32_16x16x32_bf16(af[mi], bfr[ni], acc[mi][ni], 0, 0, 0);
  }
  #pragma unroll
  for (int mi = 0; mi < 4; mi++) {
    const int row0 = m0 + wm + mi * 16 + lq * 4;
    #pragma unroll
    for (int ni = 0; ni < 4; ni++) {
      const int col = n0 + wn + ni * 16 + l16;
      #pragma unroll
      for (int j = 0; j < 4; j++) {
        const size_t idx = ((size_t)bz * M + row0 + j) * N + col;
        if (OUT_F32_BIAS) ((float*)C)[idx] = acc[mi][ni][j] + bias[row0 + j];
        else              ((u16*)C)[idx] = f2bf(acc[mi][ni][j]);
      }
    }
  }
}

// ---------------- transpose q,k sections -> [b][h][n][d] ----------------
__global__ __launch_bounds__(256) void qk_transpose(
    const u16* __restrict__ qkv, u16* __restrict__ qT, u16* __restrict__ kT) {
  __shared__ u16 T[64][72];
  const int wh = blockIdx.x;            // which*8 + h
  const int which = wh >> 3, h = wh & 7;
  const int n0 = blockIdx.y * 64, b = blockIdx.z;
  const int r = threadIdx.x >> 2, ch = (threadIdx.x & 3) * 16;
  const u16* src = qkv + (size_t)(b * 3 * C_ + which * C_ + h * D_ + r) * N_ + n0 + ch;
  us8 v1 = *(const us8*)src;
  us8 v2 = *(const us8*)(src + 8);
  *(us8*)&T[r][ch] = v1;
  *(us8*)&T[r][ch + 8] = v2;
  __syncthreads();
  us8 o1, o2;
  #pragma unroll
  for (int j = 0; j < 8; j++) { o1[j] = T[ch + j][r]; o2[j] = T[ch + 8 + j][r]; }
  u16* dst = (which ? kT : qT) + (size_t)((b * H_ + h) * N_ + n0 + r) * D_ + ch;
  *(us8*)dst = o1;
  *(us8*)(dst + 8) = o2;
}

// ---------------- flash attention v2: swapped QK^T, in-register P ----------------
// block = (h, q-tile of 128, b), 4 waves, 32 q-rows per wave.
// S^T = mfma(A=K, B=Q): lane(l16,lq) holds S[k=ni*16+lq*4+j][q=qi*16+l16].
// PV uses k-permuted fragments: a-frag slot (lq*8+t) <-> physical k =
// kh*32 + (t&4)*4 + lq*4 + (t&3); V b-frag loaded as two b64 chunks to match.
__global__ __launch_bounds__(256) void attn_kernel2(
    const u16* __restrict__ qT, const u16* __restrict__ kT,
    const u16* __restrict__ qkv, u16* __restrict__ innerT) {
  __shared__ u16 Ks[2][64][72];
  __shared__ u16 Vs[2][64][72];

  const int h = blockIdx.x, b = blockIdx.z;
  const int q0 = blockIdx.y * 128;
  const int tid = threadIdx.x;
  const int wave = tid >> 6, lane = tid & 63;
  const int l16 = lane & 15, lq = lane >> 4;

  // Q fragments in registers (B-operand: lane row = q_local = l16)
  bf16x8 qf[2][2];
  {
    const u16* qb = qT + ((size_t)((b * H_ + h) * N_ + q0 + wave * 32)) * D_;
    #pragma unroll
    for (int qi = 0; qi < 2; qi++)
      #pragma unroll
      for (int dh = 0; dh < 2; dh++)
        qf[qi][dh] = *(const bf16x8*)(qb + (size_t)(qi * 16 + l16) * D_ + dh * 32 + lq * 8);
  }

  float m[2] = {-1e30f, -1e30f};
  float l[2] = {0.f, 0.f};
  f32x4 acc[2][4];
  #pragma unroll
  for (int qi = 0; qi < 2; qi++)
    #pragma unroll
    for (int di = 0; di < 4; di++) {
      acc[qi][di][0] = 0.f; acc[qi][di][1] = 0.f; acc[qi][di][2] = 0.f; acc[qi][di][3] = 0.f;
    }

  const u16* kbase = kT + (size_t)(b * H_ + h) * N_ * D_;
  const u16* vbase = qkv + ((size_t)(b * 3 * C_) + 2 * C_ + h * D_) * N_;
  const int sr = tid >> 2, sc = (tid & 3) * 16;

  // prologue: stage tile 0
  {
    const size_t krow = (size_t)sr * D_;
    const size_t vrow = (size_t)sr * N_;
    *(us8*)&Ks[0][sr][sc]     = *(const us8*)&kbase[krow + sc];
    *(us8*)&Ks[0][sr][sc + 8] = *(const us8*)&kbase[krow + sc + 8];
    *(us8*)&Vs[0][sr][sc]     = *(const us8*)&vbase[vrow + sc];
    *(us8*)&Vs[0][sr][sc + 8] = *(const us8*)&vbase[vrow + sc + 8];
  }

  int cur = 0;
  for (int kt = 0; kt < N_ / 64; kt++) {
    __syncthreads();

    // issue next-tile loads early (complete under the MFMA phase)
    us8 nk0, nk1, nv0, nv1;
    const bool more = (kt + 1 < N_ / 64);
    if (more) {
      const size_t krow = (size_t)((kt + 1) * 64 + sr) * D_;
      nk0 = *(const us8*)&kbase[krow + sc];
      nk1 = *(const us8*)&kbase[krow + sc + 8];
      const size_t vrow = (size_t)sr * N_ + (kt + 1) * 64;
      nv0 = *(const us8*)&vbase[vrow + sc];
      nv1 = *(const us8*)&vbase[vrow + sc + 8];
    }

    // ---- S^T = K Q^T ----
    f32x4 s[2][4];
    #pragma unroll
    for (int qi = 0; qi < 2; qi++)
      #pragma unroll
      for (int ni = 0; ni < 4; ni++) {
        s[qi][ni][0] = 0.f; s[qi][ni][1] = 0.f; s[qi][ni][2] = 0.f; s[qi][ni][3] = 0.f;
      }
    #pragma unroll
    for (int ni = 0; ni < 4; ni++) {
      const bf16x8 k0 = *(const bf16x8*)&Ks[cur][ni * 16 + l16][lq * 8];
      const bf16x8 k1 = *(const bf16x8*)&Ks[cur][ni * 16 + l16][32 + lq * 8];
      #pragma unroll
      for (int qi = 0; qi < 2; qi++) {
        s[qi][ni] = __builtin_amdgcn_mfma_f32_16x16x32_bf16(k0, qf[qi][0], s[qi][ni], 0, 0, 0);
        s[qi][ni] = __builtin_amdgcn_mfma_f32_16x16x32_bf16(k1, qf[qi][1], s[qi][ni], 0, 0, 0);
      }
    }

    // ---- online softmax, exp2 domain ----
    float mt[2];
    #pragma unroll
    for (int qi = 0; qi < 2; qi++) {
      float a = fmaxf(fmaxf(s[qi][0][0], s[qi][0][1]), fmaxf(s[qi][0][2], s[qi][0][3]));
      #pragma unroll
      for (int ni = 1; ni < 4; ni++) {
        a = fmaxf(a, fmaxf(fmaxf(s[qi][ni][0], s[qi][ni][1]), fmaxf(s[qi][ni][2], s[qi][ni][3])));
      }
      a = fmaxf(a, __shfl_xor(a, 16));
      a = fmaxf(a, __shfl_xor(a, 32));
      mt[qi] = a;
    }
    // defer-max: skip rescale while growth <= 8 (p bounded by 2^8)
    const bool need = !__all((mt[0] <= m[0] + 8.f) && (mt[1] <= m[1] + 8.f));
    if (need) {
      float alpha[2];
      #pragma unroll
      for (int qi = 0; qi < 2; qi++) {
        const float mn = fmaxf(m[qi], mt[qi]);
        alpha[qi] = exp2f(m[qi] - mn);
        m[qi] = mn;
        l[qi] *= alpha[qi];
      }
      #pragma unroll
      for (int qi = 0; qi < 2; qi++)
        #pragma unroll
        for (int j = 0; j < 4; j++) {
          const float aj = __shfl(alpha[qi], lq * 4 + j);
          #pragma unroll
          for (int di = 0; di < 4; di++) acc[qi][di][j] *= aj;
        }
    }

    u32 pk[2][4][2];
    #pragma unroll
    for (int qi = 0; qi < 2; qi++) {
      float rs = 0.f;
      #pragma unroll
      for (int ni = 0; ni < 4; ni++) {
        #pragma unroll
        for (int j = 0; j < 4; j++) {
          const float p = exp2f(s[qi][ni][j] - m[qi]);
          s[qi][ni][j] = p;
          rs += p;
        }
        pk[qi][ni][0] = pack2bf(s[qi][ni][0], s[qi][ni][1]);
        pk[qi][ni][1] = pack2bf(s[qi][ni][2], s[qi][ni][3]);
      }
      rs += __shfl_xor(rs, 16);
      rs += __shfl_xor(rs, 32);
      l[qi] += rs;
    }

    // ---- PV (k-permuted fragments) ----
    #pragma unroll
    for (int kh = 0; kh < 2; kh++) {
      union { u32 w[4]; bf16x8 v; } af[2];
      #pragma unroll
      for (int qi = 0; qi < 2; qi++) {
        af[qi].w[0] = pk[qi][kh * 2][0];
        af[qi].w[1] = pk[qi][kh * 2][1];
        af[qi].w[2] = pk[qi][kh * 2 + 1][0];
        af[qi].w[3] = pk[qi][kh * 2 + 1][1];
      }
      #pragma unroll
      for (int di = 0; di < 4; di++) {
        const int vrow = di * 16 + l16;
        union { us4 q[2]; bf16x8 v; } vf;
        vf.q[0] = *(const us4*)&Vs[cur][vrow][kh * 32 + lq * 4];
        vf.q[1] = *(const us4*)&Vs[cur][vrow][kh * 32 + 16 + lq * 4];
        #pragma unroll
        for (int qi = 0; qi < 2; qi++)
          acc[qi][di] = __builtin_amdgcn_mfma_f32_16x16x32_bf16(af[qi].v, vf.v, acc[qi][di], 0, 0, 0);
      }
    }

    // late LDS write of the prefetched tile
    if (more) {
      *(us8*)&Ks[cur ^ 1][sr][sc]     = nk0;
      *(us8*)&Ks[cur ^ 1][sr][sc + 8] = nk1;
      *(us8*)&Vs[cur ^ 1][sr][sc]     = nv0;
      *(us8*)&Vs[cur ^ 1][sr][sc + 8] = nv1;
    }
    cur ^= 1;
  }

  // ---- epilogue: normalize and store ----
  float rin[2][4];
  #pragma unroll
  for (int qi = 0; qi < 2; qi++)
    #pragma unroll
    for (int j = 0; j < 4; j++)
      rin[qi][j] = 1.f / __shfl(l[qi], lq * 4 + j);

  u16* ob = innerT + ((size_t)(b * N_ + q0 + wave * 32)) * (H_ * D_) + h * D_;
  #pragma unroll
  for (int qi = 0; qi < 2; qi++)
    #pragma unroll
    for (int di = 0; di < 4; di++)
      #pragma unroll
      for (int j = 0; j < 4; j++)
        ob[(size_t)(qi * 16 + lq * 4 + j) * (H_ * D_) + di * 16 + l16] =
            f2bf(acc[qi][di][j] * rin[qi][j]);
}

extern "C" void kernel_launch(void* const* d_in, const int* in_sizes, int n_in,
                              void* d_out, int out_size, void* d_ws, size_t ws_size,
                              hipStream_t stream) {
  const float* x     = (const float*)d_in[0];
  const float* gamma = (const float*)d_in[1];
  const float* beta  = (const float*)d_in[2];
  const float* w_qkv = (const float*)d_in[3];
  const float* w_out = (const float*)d_in[4];
  const float* b_out = (const float*)d_in[5];
  float* out = (float*)d_out;

  char* ws = (char*)d_ws;
  u16*    xnT    = (u16*)(ws + 0);
  u16*    qkv    = (u16*)(ws + 9437184);
  u16*    qT     = (u16*)(ws + 37748736);
  u16*    kT     = (u16*)(ws + 47185920);
  u16*    innerT = (u16*)(ws + 56623104);
  u16*    wq_bf  = (u16*)(ws + 66060288);
  u16*    wo_bf  = (u16*)(ws + 67633152);
  float2* stats  = (float2*)(ws + 68157440);

  cast_weights<<<dim3(256), dim3(256), 0, stream>>>(w_qkv, w_out, wq_bf, wo_bf);
  gn_stats<<<dim3(B_ * G_), dim3(256), 0, stream>>>(x, stats);
  gn_apply_t<<<dim3(C_ / 64, N_ / 64, B_), dim3(256), 0, stream>>>(x, stats, gamma, beta, xnT);
  gemm_bf16<false><<<dim3(12, 18, B_), dim3(256), 0, stream>>>(wq_bf, xnT, (void*)qkv, nullptr, 1536, N_, C_);
  qk_transpose<<<dim3(16, N_ / 64, B_), dim3(256), 0, stream>>>(qkv, qT, kT);
  attn_kernel2<<<dim3(H_, N_ / 128, B_), dim3(256), 0, stream>>>(qT, kT, qkv, innerT);
  gemm_bf16<true><<<dim3(4, 18, B_), dim3(256), 0, stream>>>(wo_bf, innerT, (void*)out, b_out, C_, N_, C_);
}

// Round 3
// 191.353 us; speedup vs baseline: 1.4013x; 1.0370x over previous
//
#include <hip/hip_runtime.h>
#include <hip/hip_bf16.h>

// SelfAttention fused pipeline, bf16 MFMA path.
// x[4,512,48,48] -> GN(32 groups) -> qkv 1x1 conv -> 8-head attn (N=2304,D=64) -> out proj.
// ws layout:
//   xnT   [4][2304][512] bf16   @ 0
//   qkv   [4][1536][2304] bf16  @ 9437184      (only v rows 1024-1535 used; d-major)
//   qT    [4][8][2304][64] bf16 @ 37748736     (scale log2(e)/8 folded into W_q)
//   kT    [4][8][2304][64] bf16 @ 47185920
//   innerT[4][2304][512] bf16   @ 56623104
//   wq_bf [1536][512] bf16      @ 66060288
//   wo_bf [512][512]  bf16      @ 67633152
//   stats [4][32] float2        @ 68157440

typedef unsigned short u16;
typedef unsigned int u32;
typedef __attribute__((ext_vector_type(8))) short bf16x8;
typedef __attribute__((ext_vector_type(4))) float f32x4;
typedef __attribute__((ext_vector_type(8))) unsigned short us8;
typedef __attribute__((ext_vector_type(4))) unsigned short us4;

#define B_ 4
#define C_ 512
#define N_ 2304
#define H_ 8
#define D_ 64
#define G_ 32

// log2(e)/8: folded into W_q so QK^T lands directly in exp2 domain.
#define QSCALE 0.1803368801111204f
// fixed softmax max (exp2 domain). Scores are ~N(0,1.44), |s|max ~ 9; softmax is
// shift-invariant so any constant works while exp2(s-M) stays in f32 range.
#define FIXEDM 20.0f

__device__ __forceinline__ u16 f2bf(float f) {
  unsigned u = __float_as_uint(f);
  u += 0x7FFFu + ((u >> 16) & 1u);   // RNE
  return (u16)(u >> 16);
}

__device__ __forceinline__ u32 pack2bf(float lo, float hi) {
  __hip_bfloat162 t = __float22bfloat162_rn(float2{lo, hi});
  u32 r;
  __builtin_memcpy(&r, &t, 4);
  return r;
}

// ---------------- weight cast (q rows pre-scaled) ----------------
__global__ __launch_bounds__(256) void cast_weights(
    const float* __restrict__ wq, const float* __restrict__ wo,
    u16* __restrict__ wq_bf, u16* __restrict__ wo_bf) {
  const int n1 = 1536 * 512 / 4, n2 = 512 * 512 / 4;
  const int nq = 512 * 512 / 4;   // q section in float4 units
  for (int i = blockIdx.x * 256 + threadIdx.x; i < n1 + n2; i += gridDim.x * 256) {
    const float4 v = (i < n1) ? ((const float4*)wq)[i] : ((const float4*)wo)[i - n1];
    const float sc = (i < nq) ? QSCALE : 1.0f;
    us4 o; o[0] = f2bf(v.x * sc); o[1] = f2bf(v.y * sc); o[2] = f2bf(v.z * sc); o[3] = f2bf(v.w * sc);
    if (i < n1) ((us4*)wq_bf)[i] = o; else ((us4*)wo_bf)[i - n1] = o;
  }
}

// ---------------- groupnorm stats: one block per (b,g) ----------------
__global__ __launch_bounds__(256) void gn_stats(const float* __restrict__ x,
                                                float2* __restrict__ stats) {
  const int bg = blockIdx.x;
  const float* p = x + (size_t)bg * 16 * N_;
  float s = 0.f, s2 = 0.f;
  for (int i = threadIdx.x; i < 16 * N_ / 4; i += 256) {
    const float4 v = ((const float4*)p)[i];
    s  += v.x + v.y + v.z + v.w;
    s2 += v.x * v.x + v.y * v.y + v.z * v.z + v.w * v.w;
  }
  #pragma unroll
  for (int off = 32; off; off >>= 1) { s += __shfl_down(s, off); s2 += __shfl_down(s2, off); }
  __shared__ float red[8];
  if ((threadIdx.x & 63) == 0) { red[(threadIdx.x >> 6) * 2] = s; red[(threadIdx.x >> 6) * 2 + 1] = s2; }
  __syncthreads();
  if (threadIdx.x == 0) {
    float S = 0.f, S2 = 0.f;
    for (int w = 0; w < 4; w++) { S += red[w * 2]; S2 += red[w * 2 + 1]; }
    const float inv = 1.f / (16.f * N_);
    const float mean = S * inv;
    const float var = S2 * inv - mean * mean;
    stats[bg] = make_float2(mean, rsqrtf(var + 1e-5f));
  }
}

// ---------------- GN apply + transpose -> xnT[b][n][c] bf16 ----------------
__global__ __launch_bounds__(256) void gn_apply_t(
    const float* __restrict__ x, const float2* __restrict__ stats,
    const float* __restrict__ gamma, const float* __restrict__ beta,
    u16* __restrict__ xnT) {
  __shared__ u16 T[64][72];
  const int c0 = blockIdx.x * 64, n0 = blockIdx.y * 64, b = blockIdx.z;
  const int r = threadIdx.x >> 2, ch = (threadIdx.x & 3) * 16;
  const int cc = c0 + r;
  const float2 st = stats[b * G_ + (cc >> 4)];
  const float sc = st.y * gamma[cc];
  const float sh = beta[cc] - st.x * sc;
  const float* src = x + (size_t)(b * C_ + cc) * N_ + n0 + ch;
  #pragma unroll
  for (int j = 0; j < 16; j += 4) {
    const float4 v = *(const float4*)(src + j);
    us4 o; o[0] = f2bf(v.x * sc + sh); o[1] = f2bf(v.y * sc + sh);
    o[2] = f2bf(v.z * sc + sh); o[3] = f2bf(v.w * sc + sh);
    *(us4*)&T[r][ch + j] = o;
  }
  __syncthreads();
  us8 o1, o2;
  #pragma unroll
  for (int j = 0; j < 8; j++) { o1[j] = T[ch + j][r]; o2[j] = T[ch + 8 + j][r]; }
  u16* dst = xnT + (size_t)(b * N_ + n0 + r) * C_ + c0 + ch;
  *(us8*)dst = o1;
  *(us8*)(dst + 8) = o2;
}

// ---------------- GEMM: C[bz][m][n] = A[m][k] * B[bz][n][k]^T ----------------
// MODE 1: f32 output + bias (final projection).
// MODE 2: qkv split epilogue: q rows -> qT[b][h][n][d], k rows -> kT[b][h][n][d],
//         v rows -> qkv[b][o][n] (d-major, as attention consumes it).
template <int MODE>
__global__ __launch_bounds__(256) void gemm_bf16(
    const u16* __restrict__ A, const u16* __restrict__ B,
    void* __restrict__ C, const float* __restrict__ bias,
    u16* __restrict__ qT, u16* __restrict__ kT,
    const int M, const int N, const int K) {
  __shared__ u16 As[128][40];
  __shared__ u16 Bs[128][40];
  const int tid = threadIdx.x;
  const int wave = tid >> 6, lane = tid & 63;
  const int l16 = lane & 15, lq = lane >> 4;
  const int m0 = blockIdx.x * 128, n0 = blockIdx.y * 128, bz = blockIdx.z;
  const int wm = (wave >> 1) * 64, wn = (wave & 1) * 64;
  const u16* Bb = B + (size_t)bz * N * K;

  f32x4 acc[4][4];
  #pragma unroll
  for (int mi = 0; mi < 4; mi++)
    #pragma unroll
    for (int ni = 0; ni < 4; ni++) {
      acc[mi][ni][0] = 0.f; acc[mi][ni][1] = 0.f; acc[mi][ni][2] = 0.f; acc[mi][ni][3] = 0.f;
    }

  const int r = tid >> 2, c = (tid & 3) * 8;
  for (int kt = 0; kt < K; kt += 32) {
    __syncthreads();
    *(us8*)&As[r][c]      = *(const us8*)&A[(size_t)(m0 + r) * K + kt + c];
    *(us8*)&As[r + 64][c] = *(const us8*)&A[(size_t)(m0 + r + 64) * K + kt + c];
    *(us8*)&Bs[r][c]      = *(const us8*)&Bb[(size_t)(n0 + r) * K + kt + c];
    *(us8*)&Bs[r + 64][c] = *(const us8*)&Bb[(size_t)(n0 + r + 64) * K + kt + c];
    __syncthreads();
    bf16x8 af[4], bfr[4];
    #pragma unroll
    for (int mi = 0; mi < 4; mi++) af[mi] = *(const bf16x8*)&As[wm + mi * 16 + l16][lq * 8];
    #pragma unroll
    for (int ni = 0; ni < 4; ni++) bfr[ni] = *(const bf16x8*)&Bs[wn + ni * 16 + l16][lq * 8];
    #pragma unroll
    for (int mi = 0; mi < 4; mi++)
      #pragma unroll
      for (int ni = 0; ni < 4; ni++)
        acc[mi][ni] = __builtin_amdgcn_mfma_f32_16x16x32_bf16(af[mi], bfr[ni], acc[mi][ni], 0, 0, 0);
  }
  #pragma unroll
  for (int mi = 0; mi < 4; mi++) {
    const int row0 = m0 + wm + mi * 16 + lq * 4;
    #pragma unroll
    for (int ni = 0; ni < 4; ni++) {
      const int col = n0 + wn + ni * 16 + l16;
      if (MODE == 1) {
        #pragma unroll
        for (int j = 0; j < 4; j++) {
          const size_t idx = ((size_t)bz * M + row0 + j) * N + col;
          ((float*)C)[idx] = acc[mi][ni][j] + bias[row0 + j];
        }
      } else {
        const int which = row0 >> 9;           // 0=q, 1=k, 2=v
        if (which < 2) {
          const int h = (row0 >> 6) & 7, d0 = row0 & 63;
          u16* dst = which ? kT : qT;
          us4 o;
          #pragma unroll
          for (int j = 0; j < 4; j++) o[j] = f2bf(acc[mi][ni][j]);
          *(us4*)&dst[((size_t)((bz * H_ + h) * N_) + col) * D_ + d0] = o;
        } else {
          #pragma unroll
          for (int j = 0; j < 4; j++)
            ((u16*)C)[((size_t)bz * M + row0 + j) * N + col] = f2bf(acc[mi][ni][j]);
        }
      }
    }
  }
}

// ---------------- flash attention v3: swapped QK^T, fixed-max softmax ----------------
// block = (h, q-tile of 128, b), 4 waves, 32 q-rows per wave.
// S^T = mfma(A=K, B=Q): lane(l16,lq) holds S[k=ni*16+lq*4+j][q=qi*16+l16], init -FIXEDM.
// No max tracking, no cross-lane ops in the loop: p = exp2(s), l accumulates in-lane.
// V staged k-PERMUTED in LDS so the PV b-frag is a single b128 read:
//   col' = lq*8 + hi*4 + j  <-  orig n_local = hi*16 + lq*4 + j  (per 32-col group)
__global__ __launch_bounds__(256) void attn_kernel3(
    const u16* __restrict__ qT, const u16* __restrict__ kT,
    const u16* __restrict__ qkv, u16* __restrict__ innerT) {
  __shared__ u16 Ks[2][64][72];
  __shared__ u16 Vs[2][64][72];

  const int h = blockIdx.x, b = blockIdx.z;
  const int q0 = blockIdx.y * 128;
  const int tid = threadIdx.x;
  const int wave = tid >> 6, lane = tid & 63;
  const int l16 = lane & 15, lq = lane >> 4;

  // Q fragments in registers (B-operand: lane row = q_local = l16)
  bf16x8 qf[2][2];
  {
    const u16* qb = qT + ((size_t)((b * H_ + h) * N_ + q0 + wave * 32)) * D_;
    #pragma unroll
    for (int qi = 0; qi < 2; qi++)
      #pragma unroll
      for (int dh = 0; dh < 2; dh++)
        qf[qi][dh] = *(const bf16x8*)(qb + (size_t)(qi * 16 + l16) * D_ + dh * 32 + lq * 8);
  }

  float l[2] = {0.f, 0.f};
  f32x4 acc[2][4];
  #pragma unroll
  for (int qi = 0; qi < 2; qi++)
    #pragma unroll
    for (int di = 0; di < 4; di++) {
      acc[qi][di][0] = 0.f; acc[qi][di][1] = 0.f; acc[qi][di][2] = 0.f; acc[qi][di][3] = 0.f;
    }

  const u16* kbase = kT + (size_t)(b * H_ + h) * N_ * D_;
  const u16* vbase = qkv + ((size_t)(b * 3 * C_) + 2 * C_ + h * D_) * N_;
  const int sr = tid >> 2, sc = (tid & 3) * 16;
  // permuted V columns for the two us8 chunks this thread stages
  const int cb1 = sc & 31, cb2 = (sc + 8) & 31;
  const int colp1 = (sc & ~31) + ((cb1 >> 2) & 3) * 8 + ((cb1 >> 4) & 1) * 4;
  const int colp2 = ((sc + 8) & ~31) + ((cb2 >> 2) & 3) * 8 + ((cb2 >> 4) & 1) * 4;

  // prologue: stage tile 0
  {
    const size_t krow = (size_t)sr * D_;
    const size_t vrow = (size_t)sr * N_;
    *(us8*)&Ks[0][sr][sc]     = *(const us8*)&kbase[krow + sc];
    *(us8*)&Ks[0][sr][sc + 8] = *(const us8*)&kbase[krow + sc + 8];
    us8 v0 = *(const us8*)&vbase[vrow + sc];
    us8 v1 = *(const us8*)&vbase[vrow + sc + 8];
    *(us4*)&Vs[0][sr][colp1]     = ((us4*)&v0)[0];
    *(us4*)&Vs[0][sr][colp1 + 8] = ((us4*)&v0)[1];
    *(us4*)&Vs[0][sr][colp2]     = ((us4*)&v1)[0];
    *(us4*)&Vs[0][sr][colp2 + 8] = ((us4*)&v1)[1];
  }

  int cur = 0;
  for (int kt = 0; kt < N_ / 64; kt++) {
    __syncthreads();

    // issue next-tile loads early (complete under the MFMA phase)
    us8 nk0, nk1, nv0, nv1;
    const bool more = (kt + 1 < N_ / 64);
    if (more) {
      const size_t krow = (size_t)((kt + 1) * 64 + sr) * D_;
      nk0 = *(const us8*)&kbase[krow + sc];
      nk1 = *(const us8*)&kbase[krow + sc + 8];
      const size_t vrow = (size_t)sr * N_ + (kt + 1) * 64;
      nv0 = *(const us8*)&vbase[vrow + sc];
      nv1 = *(const us8*)&vbase[vrow + sc + 8];
    }

    // ---- S^T = K Q^T (acc init -FIXEDM folds the max subtraction) ----
    f32x4 s[2][4];
    #pragma unroll
    for (int qi = 0; qi < 2; qi++)
      #pragma unroll
      for (int ni = 0; ni < 4; ni++) {
        s[qi][ni][0] = -FIXEDM; s[qi][ni][1] = -FIXEDM;
        s[qi][ni][2] = -FIXEDM; s[qi][ni][3] = -FIXEDM;
      }
    __builtin_amdgcn_s_setprio(1);
    #pragma unroll
    for (int ni = 0; ni < 4; ni++) {
      const bf16x8 k0 = *(const bf16x8*)&Ks[cur][ni * 16 + l16][lq * 8];
      const bf16x8 k1 = *(const bf16x8*)&Ks[cur][ni * 16 + l16][32 + lq * 8];
      #pragma unroll
      for (int qi = 0; qi < 2; qi++) {
        s[qi][ni] = __builtin_amdgcn_mfma_f32_16x16x32_bf16(k0, qf[qi][0], s[qi][ni], 0, 0, 0);
        s[qi][ni] = __builtin_amdgcn_mfma_f32_16x16x32_bf16(k1, qf[qi][1], s[qi][ni], 0, 0, 0);
      }
    }
    __builtin_amdgcn_s_setprio(0);

    // ---- p = exp2(s); accumulate l in-lane; pack to bf16 ----
    u32 pk[2][4][2];
    #pragma unroll
    for (int qi = 0; qi < 2; qi++) {
      float rs = 0.f;
      #pragma unroll
      for (int ni = 0; ni < 4; ni++) {
        float p0 = exp2f(s[qi][ni][0]);
        float p1 = exp2f(s[qi][ni][1]);
        float p2 = exp2f(s[qi][ni][2]);
        float p3 = exp2f(s[qi][ni][3]);
        rs += (p0 + p1) + (p2 + p3);
        pk[qi][ni][0] = pack2bf(p0, p1);
        pk[qi][ni][1] = pack2bf(p2, p3);
      }
      l[qi] += rs;
    }

    // ---- PV: b128 V reads (k-permutation pre-applied at staging) ----
    __builtin_amdgcn_s_setprio(1);
    #pragma unroll
    for (int kh = 0; kh < 2; kh++) {
      union { u32 w[4]; bf16x8 v; } af[2];
      #pragma unroll
      for (int qi = 0; qi < 2; qi++) {
        af[qi].w[0] = pk[qi][kh * 2][0];
        af[qi].w[1] = pk[qi][kh * 2][1];
        af[qi].w[2] = pk[qi][kh * 2 + 1][0];
        af[qi].w[3] = pk[qi][kh * 2 + 1][1];
      }
      #pragma unroll
      for (int di = 0; di < 4; di++) {
        const bf16x8 vf = *(const bf16x8*)&Vs[cur][di * 16 + l16][kh * 32 + lq * 8];
        #pragma unroll
        for (int qi = 0; qi < 2; qi++)
          acc[qi][di] = __builtin_amdgcn_mfma_f32_16x16x32_bf16(af[qi].v, vf, acc[qi][di], 0, 0, 0);
      }
    }
    __builtin_amdgcn_s_setprio(0);

    // late LDS write of the prefetched tile
    if (more) {
      *(us8*)&Ks[cur ^ 1][sr][sc]     = nk0;
      *(us8*)&Ks[cur ^ 1][sr][sc + 8] = nk1;
      *(us4*)&Vs[cur ^ 1][sr][colp1]     = ((us4*)&nv0)[0];
      *(us4*)&Vs[cur ^ 1][sr][colp1 + 8] = ((us4*)&nv0)[1];
      *(us4*)&Vs[cur ^ 1][sr][colp2]     = ((us4*)&nv1)[0];
      *(us4*)&Vs[cur ^ 1][sr][colp2 + 8] = ((us4*)&nv1)[1];
    }
    cur ^= 1;
  }

  // ---- epilogue: reduce l across lq groups, normalize, store ----
  #pragma unroll
  for (int qi = 0; qi < 2; qi++) {
    l[qi] += __shfl_xor(l[qi], 16);
    l[qi] += __shfl_xor(l[qi], 32);
  }
  float rin[2][4];
  #pragma unroll
  for (int qi = 0; qi < 2; qi++)
    #pragma unroll
    for (int j = 0; j < 4; j++)
      rin[qi][j] = 1.f / __shfl(l[qi], lq * 4 + j);

  u16* ob = innerT + ((size_t)(b * N_ + q0 + wave * 32)) * (H_ * D_) + h * D_;
  #pragma unroll
  for (int qi = 0; qi < 2; qi++)
    #pragma unroll
    for (int di = 0; di < 4; di++)
      #pragma unroll
      for (int j = 0; j < 4; j++)
        ob[(size_t)(qi * 16 + lq * 4 + j) * (H_ * D_) + di * 16 + l16] =
            f2bf(acc[qi][di][j] * rin[qi][j]);
}

extern "C" void kernel_launch(void* const* d_in, const int* in_sizes, int n_in,
                              void* d_out, int out_size, void* d_ws, size_t ws_size,
                              hipStream_t stream) {
  const float* x     = (const float*)d_in[0];
  const float* gamma = (const float*)d_in[1];
  const float* beta  = (const float*)d_in[2];
  const float* w_qkv = (const float*)d_in[3];
  const float* w_out = (const float*)d_in[4];
  const float* b_out = (const float*)d_in[5];
  float* out = (float*)d_out;

  char* ws = (char*)d_ws;
  u16*    xnT    = (u16*)(ws + 0);
  u16*    qkv    = (u16*)(ws + 9437184);
  u16*    qT     = (u16*)(ws + 37748736);
  u16*    kT     = (u16*)(ws + 47185920);
  u16*    innerT = (u16*)(ws + 56623104);
  u16*    wq_bf  = (u16*)(ws + 66060288);
  u16*    wo_bf  = (u16*)(ws + 67633152);
  float2* stats  = (float2*)(ws + 68157440);

  cast_weights<<<dim3(256), dim3(256), 0, stream>>>(w_qkv, w_out, wq_bf, wo_bf);
  gn_stats<<<dim3(B_ * G_), dim3(256), 0, stream>>>(x, stats);
  gn_apply_t<<<dim3(C_ / 64, N_ / 64, B_), dim3(256), 0, stream>>>(x, stats, gamma, beta, xnT);
  gemm_bf16<2><<<dim3(12, 18, B_), dim3(256), 0, stream>>>(wq_bf, xnT, (void*)qkv, nullptr, qT, kT, 1536, N_, C_);
  attn_kernel3<<<dim3(H_, N_ / 128, B_), dim3(256), 0, stream>>>(qT, kT, qkv, innerT);
  gemm_bf16<1><<<dim3(4, 18, B_), dim3(256), 0, stream>>>(wo_bf, innerT, (void*)out, b_out, nullptr, nullptr, C_, N_, C_);
}

// Round 4
// 188.277 us; speedup vs baseline: 1.4242x; 1.0163x over previous
//
#include <hip/hip_runtime.h>
#include <hip/hip_bf16.h>

// SelfAttention fused pipeline, bf16 MFMA path, K-split flash attention.
// x[4,512,48,48] -> GN(32) -> qkv 1x1 conv -> 8-head attn (N=2304,D=64) -> out proj.
//
// ws layout (66.66 MB, < 68.16 MB proven safe):
//   po0  [4][2304][512] f32 @ 0          (first 9.44 MB doubles as xnT before attn)
//   po1  [4][2304][512] f32 @ 18874368
//   v    [4][512][2304] bf16 @ 37748736  (d-major, PV B-operand layout)
//   qT   [4][8][2304][64] bf16 @ 47185920 (QSCALE folded via W_q staging)
//   kT   [4][8][2304][64] bf16 @ 56623104
//   pl   [2][4][8][2304] f32 @ 66060288
//   stats[4][32] float2     @ 66650112
// xnT [4][2304][512] bf16 @ 0 (aliases po0; dead once gemm1 completes)

typedef unsigned short u16;
typedef unsigned int u32;
typedef __attribute__((ext_vector_type(8))) short bf16x8;
typedef __attribute__((ext_vector_type(4))) float f32x4;
typedef __attribute__((ext_vector_type(8))) unsigned short us8;
typedef __attribute__((ext_vector_type(4))) unsigned short us4;

#define B_ 4
#define C_ 512
#define N_ 2304
#define H_ 8
#define D_ 64
#define G_ 32
#define SPLIT 2
#define NT (N_ / 64 / SPLIT)   // 18 k-tiles per split block

// log2(e)/8: folded into W_q at staging so QK^T lands in exp2 domain.
#define QSCALE 0.1803368801111204f
// fixed softmax max (exp2 domain): scores ~N(0,1.44), softmax shift-invariant.
#define FIXEDM 20.0f

__device__ __forceinline__ u16 f2bf(float f) {
  unsigned u = __float_as_uint(f);
  u += 0x7FFFu + ((u >> 16) & 1u);   // RNE
  return (u16)(u >> 16);
}

__device__ __forceinline__ u32 pack2bf(float lo, float hi) {
  __hip_bfloat162 t = __float22bfloat162_rn(float2{lo, hi});
  u32 r;
  __builtin_memcpy(&r, &t, 4);
  return r;
}

// ---------------- groupnorm stats: one block per (b,g) ----------------
__global__ __launch_bounds__(256) void gn_stats(const float* __restrict__ x,
                                                float2* __restrict__ stats) {
  const int bg = blockIdx.x;
  const float* p = x + (size_t)bg * 16 * N_;
  float s = 0.f, s2 = 0.f;
  for (int i = threadIdx.x; i < 16 * N_ / 4; i += 256) {
    const float4 v = ((const float4*)p)[i];
    s  += v.x + v.y + v.z + v.w;
    s2 += v.x * v.x + v.y * v.y + v.z * v.z + v.w * v.w;
  }
  #pragma unroll
  for (int off = 32; off; off >>= 1) { s += __shfl_down(s, off); s2 += __shfl_down(s2, off); }
  __shared__ float red[8];
  if ((threadIdx.x & 63) == 0) { red[(threadIdx.x >> 6) * 2] = s; red[(threadIdx.x >> 6) * 2 + 1] = s2; }
  __syncthreads();
  if (threadIdx.x == 0) {
    float S = 0.f, S2 = 0.f;
    for (int w = 0; w < 4; w++) { S += red[w * 2]; S2 += red[w * 2 + 1]; }
    const float inv = 1.f / (16.f * N_);
    const float mean = S * inv;
    const float var = S2 * inv - mean * mean;
    stats[bg] = make_float2(mean, rsqrtf(var + 1e-5f));
  }
}

// ---------------- GN apply + transpose -> xnT[b][n][c] bf16 ----------------
__global__ __launch_bounds__(256) void gn_apply_t(
    const float* __restrict__ x, const float2* __restrict__ stats,
    const float* __restrict__ gamma, const float* __restrict__ beta,
    u16* __restrict__ xnT) {
  __shared__ u16 T[64][72];
  const int c0 = blockIdx.x * 64, n0 = blockIdx.y * 64, b = blockIdx.z;
  const int r = threadIdx.x >> 2, ch = (threadIdx.x & 3) * 16;
  const int cc = c0 + r;
  const float2 st = stats[b * G_ + (cc >> 4)];
  const float sc = st.y * gamma[cc];
  const float sh = beta[cc] - st.x * sc;
  const float* src = x + (size_t)(b * C_ + cc) * N_ + n0 + ch;
  #pragma unroll
  for (int j = 0; j < 16; j += 4) {
    const float4 v = *(const float4*)(src + j);
    us4 o; o[0] = f2bf(v.x * sc + sh); o[1] = f2bf(v.y * sc + sh);
    o[2] = f2bf(v.z * sc + sh); o[3] = f2bf(v.w * sc + sh);
    *(us4*)&T[r][ch + j] = o;
  }
  __syncthreads();
  us8 o1, o2;
  #pragma unroll
  for (int j = 0; j < 8; j++) { o1[j] = T[ch + j][r]; o2[j] = T[ch + 8 + j][r]; }
  u16* dst = xnT + (size_t)(b * N_ + n0 + r) * C_ + c0 + ch;
  *(us8*)dst = o1;
  *(us8*)(dst + 8) = o2;
}

// ---------------- GEMM: C[bz][m][n] = A[m][k] * B[bz][n][k]^T ----------------
// A is f32 weights [M][K], cast to bf16 during LDS staging (MODE2: q-rows scaled).
// MODE 2 (qkv): B = xnT bf16; epilogue scatters q->qT, k->kT, v->v (d-major).
// MODE 1 (out proj): B = (po0+po1)*rl normalized at staging; out f32 + bias.
template <int MODE>
__global__ __launch_bounds__(256) void gemm_bf16(
    const float* __restrict__ Af, const u16* __restrict__ Bb16,
    const float* __restrict__ po0, const float* __restrict__ po1,
    const float* __restrict__ pl,
    void* __restrict__ C, const float* __restrict__ bias,
    u16* __restrict__ qT, u16* __restrict__ kT, u16* __restrict__ vout,
    const int M, const int N, const int K) {
  __shared__ u16 As[128][40];
  __shared__ u16 Bs[128][40];
  const int tid = threadIdx.x;
  const int wave = tid >> 6, lane = tid & 63;
  const int l16 = lane & 15, lq = lane >> 4;
  const int m0 = blockIdx.x * 128, n0 = blockIdx.y * 128, bz = blockIdx.z;
  const int wm = (wave >> 1) * 64, wn = (wave & 1) * 64;

  f32x4 acc[4][4];
  #pragma unroll
  for (int mi = 0; mi < 4; mi++)
    #pragma unroll
    for (int ni = 0; ni < 4; ni++) {
      acc[mi][ni][0] = 0.f; acc[mi][ni][1] = 0.f; acc[mi][ni][2] = 0.f; acc[mi][ni][3] = 0.f;
    }

  const int r = tid >> 2, c = (tid & 3) * 8;
  for (int kt = 0; kt < K; kt += 32) {
    __syncthreads();
    // ---- A staging: f32 -> bf16 cast (+QSCALE fold for q rows in MODE2) ----
    #pragma unroll
    for (int half = 0; half < 2; half++) {
      const int row = m0 + r + half * 64;
      const float* ap = Af + (size_t)row * K + kt + c;
      const float4 f0 = *(const float4*)ap;
      const float4 f1 = *(const float4*)(ap + 4);
      const float sc = (MODE == 2 && row < 512) ? QSCALE : 1.0f;
      us8 o;
      o[0] = f2bf(f0.x * sc); o[1] = f2bf(f0.y * sc);
      o[2] = f2bf(f0.z * sc); o[3] = f2bf(f0.w * sc);
      o[4] = f2bf(f1.x * sc); o[5] = f2bf(f1.y * sc);
      o[6] = f2bf(f1.z * sc); o[7] = f2bf(f1.w * sc);
      *(us8*)&As[r + half * 64][c] = o;
    }
    // ---- B staging ----
    if (MODE == 2) {
      const u16* Bb = Bb16 + (size_t)bz * N * K;
      *(us8*)&Bs[r][c]      = *(const us8*)&Bb[(size_t)(n0 + r) * K + kt + c];
      *(us8*)&Bs[r + 64][c] = *(const us8*)&Bb[(size_t)(n0 + r + 64) * K + kt + c];
    } else {
      const int h = (kt + c) >> 6;
      #pragma unroll
      for (int half = 0; half < 2; half++) {
        const int n = n0 + r + half * 64;
        const size_t lidx = ((size_t)(bz * H_) + h) * N_ + n;
        const float rl = 1.0f / (pl[lidx] + pl[lidx + B_ * H_ * N_]);
        const size_t pidx = ((size_t)(bz * N_) + n) * 512 + kt + c;
        const float4 a0 = *(const float4*)&po0[pidx];
        const float4 a1 = *(const float4*)&po0[pidx + 4];
        const float4 b0 = *(const float4*)&po1[pidx];
        const float4 b1 = *(const float4*)&po1[pidx + 4];
        us8 o;
        o[0] = f2bf((a0.x + b0.x) * rl); o[1] = f2bf((a0.y + b0.y) * rl);
        o[2] = f2bf((a0.z + b0.z) * rl); o[3] = f2bf((a0.w + b0.w) * rl);
        o[4] = f2bf((a1.x + b1.x) * rl); o[5] = f2bf((a1.y + b1.y) * rl);
        o[6] = f2bf((a1.z + b1.z) * rl); o[7] = f2bf((a1.w + b1.w) * rl);
        *(us8*)&Bs[r + half * 64][c] = o;
      }
    }
    __syncthreads();
    bf16x8 af[4], bfr[4];
    #pragma unroll
    for (int mi = 0; mi < 4; mi++) af[mi] = *(const bf16x8*)&As[wm + mi * 16 + l16][lq * 8];
    #pragma unroll
    for (int ni = 0; ni < 4; ni++) bfr[ni] = *(const bf16x8*)&Bs[wn + ni * 16 + l16][lq * 8];
    #pragma unroll
    for (int mi = 0; mi < 4; mi++)
      #pragma unroll
      for (int ni = 0; ni < 4; ni++)
        acc[mi][ni] = __builtin_amdgcn_mfma_f32_16x16x32_bf16(af[mi], bfr[ni], acc[mi][ni], 0, 0, 0);
  }
  #pragma unroll
  for (int mi = 0; mi < 4; mi++) {
    const int row0 = m0 + wm + mi * 16 + lq * 4;
    #pragma unroll
    for (int ni = 0; ni < 4; ni++) {
      const int col = n0 + wn + ni * 16 + l16;
      if (MODE == 1) {
        #pragma unroll
        for (int j = 0; j < 4; j++) {
          const size_t idx = ((size_t)bz * M + row0 + j) * N + col;
          ((float*)C)[idx] = acc[mi][ni][j] + bias[row0 + j];
        }
      } else {
        const int which = row0 >> 9;           // 0=q, 1=k, 2=v
        if (which < 2) {
          const int h = (row0 >> 6) & 7, d0 = row0 & 63;
          u16* dst = which ? kT : qT;
          us4 o;
          #pragma unroll
          for (int j = 0; j < 4; j++) o[j] = f2bf(acc[mi][ni][j]);
          *(us4*)&dst[((size_t)((bz * H_ + h) * N_) + col) * D_ + d0] = o;
        } else {
          #pragma unroll
          for (int j = 0; j < 4; j++)
            vout[((size_t)(bz * 512) + (row0 & 511) + j) * N + col] = f2bf(acc[mi][ni][j]);
        }
      }
    }
  }
}

// ---------------- flash attention v4: K-split, swapped QK^T, fixed-max ----------------
// block = (h, q-tile of 128, b*SPLIT+sp), 4 waves, 32 q-rows per wave, 18 k-tiles.
// Writes UNNORMALIZED partial O (f32) + partial l; normalization fused into gemm2.
__global__ __launch_bounds__(256) void attn_kernel4(
    const u16* __restrict__ qT, const u16* __restrict__ kT,
    const u16* __restrict__ vsec, float* __restrict__ po0,
    float* __restrict__ pl) {
  __shared__ u16 Ks[2][64][72];
  __shared__ u16 Vs[2][64][72];

  const int h = blockIdx.x;
  const int b = blockIdx.z >> 1, sp = blockIdx.z & 1;
  const int q0 = blockIdx.y * 128;
  const int tid = threadIdx.x;
  const int wave = tid >> 6, lane = tid & 63;
  const int l16 = lane & 15, lq = lane >> 4;
  const int kt0 = sp * NT;

  bf16x8 qf[2][2];
  {
    const u16* qb = qT + ((size_t)((b * H_ + h) * N_ + q0 + wave * 32)) * D_;
    #pragma unroll
    for (int qi = 0; qi < 2; qi++)
      #pragma unroll
      for (int dh = 0; dh < 2; dh++)
        qf[qi][dh] = *(const bf16x8*)(qb + (size_t)(qi * 16 + l16) * D_ + dh * 32 + lq * 8);
  }

  float l[2] = {0.f, 0.f};
  f32x4 acc[2][4];
  #pragma unroll
  for (int qi = 0; qi < 2; qi++)
    #pragma unroll
    for (int di = 0; di < 4; di++) {
      acc[qi][di][0] = 0.f; acc[qi][di][1] = 0.f; acc[qi][di][2] = 0.f; acc[qi][di][3] = 0.f;
    }

  const u16* kbase = kT + (size_t)(b * H_ + h) * N_ * D_;
  const u16* vbase = vsec + ((size_t)(b * 512) + h * D_) * N_;
  const int sr = tid >> 2, sc = (tid & 3) * 16;
  // permuted V columns so PV b-frag is one b128 read
  const int cb1 = sc & 31, cb2 = (sc + 8) & 31;
  const int colp1 = (sc & ~31) + ((cb1 >> 2) & 3) * 8 + ((cb1 >> 4) & 1) * 4;
  const int colp2 = ((sc + 8) & ~31) + ((cb2 >> 2) & 3) * 8 + ((cb2 >> 4) & 1) * 4;

  // prologue: stage tile kt0
  {
    const size_t krow = (size_t)(kt0 * 64 + sr) * D_;
    const size_t vrow = (size_t)sr * N_ + kt0 * 64;
    *(us8*)&Ks[0][sr][sc]     = *(const us8*)&kbase[krow + sc];
    *(us8*)&Ks[0][sr][sc + 8] = *(const us8*)&kbase[krow + sc + 8];
    us8 v0 = *(const us8*)&vbase[vrow + sc];
    us8 v1 = *(const us8*)&vbase[vrow + sc + 8];
    *(us4*)&Vs[0][sr][colp1]     = ((us4*)&v0)[0];
    *(us4*)&Vs[0][sr][colp1 + 8] = ((us4*)&v0)[1];
    *(us4*)&Vs[0][sr][colp2]     = ((us4*)&v1)[0];
    *(us4*)&Vs[0][sr][colp2 + 8] = ((us4*)&v1)[1];
  }

  int cur = 0;
  for (int t = 0; t < NT; t++) {
    const int kt = kt0 + t;
    __syncthreads();

    us8 nk0, nk1, nv0, nv1;
    const bool more = (t + 1 < NT);
    if (more) {
      const size_t krow = (size_t)((kt + 1) * 64 + sr) * D_;
      nk0 = *(const us8*)&kbase[krow + sc];
      nk1 = *(const us8*)&kbase[krow + sc + 8];
      const size_t vrow = (size_t)sr * N_ + (kt + 1) * 64;
      nv0 = *(const us8*)&vbase[vrow + sc];
      nv1 = *(const us8*)&vbase[vrow + sc + 8];
    }

    // ---- S^T = K Q^T (acc init -FIXEDM folds the max subtraction) ----
    f32x4 s[2][4];
    #pragma unroll
    for (int qi = 0; qi < 2; qi++)
      #pragma unroll
      for (int ni = 0; ni < 4; ni++) {
        s[qi][ni][0] = -FIXEDM; s[qi][ni][1] = -FIXEDM;
        s[qi][ni][2] = -FIXEDM; s[qi][ni][3] = -FIXEDM;
      }
    __builtin_amdgcn_s_setprio(1);
    #pragma unroll
    for (int ni = 0; ni < 4; ni++) {
      const bf16x8 k0 = *(const bf16x8*)&Ks[cur][ni * 16 + l16][lq * 8];
      const bf16x8 k1 = *(const bf16x8*)&Ks[cur][ni * 16 + l16][32 + lq * 8];
      #pragma unroll
      for (int qi = 0; qi < 2; qi++) {
        s[qi][ni] = __builtin_amdgcn_mfma_f32_16x16x32_bf16(k0, qf[qi][0], s[qi][ni], 0, 0, 0);
        s[qi][ni] = __builtin_amdgcn_mfma_f32_16x16x32_bf16(k1, qf[qi][1], s[qi][ni], 0, 0, 0);
      }
    }
    __builtin_amdgcn_s_setprio(0);

    // ---- p = exp2(s); accumulate l in-lane; pack to bf16 ----
    u32 pk[2][4][2];
    #pragma unroll
    for (int qi = 0; qi < 2; qi++) {
      float rs = 0.f;
      #pragma unroll
      for (int ni = 0; ni < 4; ni++) {
        float p0 = exp2f(s[qi][ni][0]);
        float p1 = exp2f(s[qi][ni][1]);
        float p2 = exp2f(s[qi][ni][2]);
        float p3 = exp2f(s[qi][ni][3]);
        rs += (p0 + p1) + (p2 + p3);
        pk[qi][ni][0] = pack2bf(p0, p1);
        pk[qi][ni][1] = pack2bf(p2, p3);
      }
      l[qi] += rs;
    }

    // ---- PV ----
    __builtin_amdgcn_s_setprio(1);
    #pragma unroll
    for (int kh = 0; kh < 2; kh++) {
      union { u32 w[4]; bf16x8 v; } af[2];
      #pragma unroll
      for (int qi = 0; qi < 2; qi++) {
        af[qi].w[0] = pk[qi][kh * 2][0];
        af[qi].w[1] = pk[qi][kh * 2][1];
        af[qi].w[2] = pk[qi][kh * 2 + 1][0];
        af[qi].w[3] = pk[qi][kh * 2 + 1][1];
      }
      #pragma unroll
      for (int di = 0; di < 4; di++) {
        const bf16x8 vf = *(const bf16x8*)&Vs[cur][di * 16 + l16][kh * 32 + lq * 8];
        #pragma unroll
        for (int qi = 0; qi < 2; qi++)
          acc[qi][di] = __builtin_amdgcn_mfma_f32_16x16x32_bf16(af[qi].v, vf, acc[qi][di], 0, 0, 0);
      }
    }
    __builtin_amdgcn_s_setprio(0);

    if (more) {
      *(us8*)&Ks[cur ^ 1][sr][sc]     = nk0;
      *(us8*)&Ks[cur ^ 1][sr][sc + 8] = nk1;
      *(us4*)&Vs[cur ^ 1][sr][colp1]     = ((us4*)&nv0)[0];
      *(us4*)&Vs[cur ^ 1][sr][colp1 + 8] = ((us4*)&nv0)[1];
      *(us4*)&Vs[cur ^ 1][sr][colp2]     = ((us4*)&nv1)[0];
      *(us4*)&Vs[cur ^ 1][sr][colp2 + 8] = ((us4*)&nv1)[1];
    }
    cur ^= 1;
  }

  // ---- epilogue: write unnormalized partial O (f32) + partial l ----
  float* po = po0 + (size_t)sp * (B_ * N_ * 512);
  #pragma unroll
  for (int qi = 0; qi < 2; qi++) {
    l[qi] += __shfl_xor(l[qi], 16);
    l[qi] += __shfl_xor(l[qi], 32);
  }
  if (lq == 0) {
    #pragma unroll
    for (int qi = 0; qi < 2; qi++) {
      const int n = q0 + wave * 32 + qi * 16 + l16;
      pl[((size_t)((sp * B_ + b) * H_) + h) * N_ + n] = l[qi];
    }
  }
  #pragma unroll
  for (int qi = 0; qi < 2; qi++)
    #pragma unroll
    for (int di = 0; di < 4; di++)
      #pragma unroll
      for (int j = 0; j < 4; j++) {
        const int n = q0 + wave * 32 + qi * 16 + lq * 4 + j;
        po[((size_t)(b * N_) + n) * 512 + h * D_ + di * 16 + l16] = acc[qi][di][j];
      }
}

extern "C" void kernel_launch(void* const* d_in, const int* in_sizes, int n_in,
                              void* d_out, int out_size, void* d_ws, size_t ws_size,
                              hipStream_t stream) {
  const float* x     = (const float*)d_in[0];
  const float* gamma = (const float*)d_in[1];
  const float* beta  = (const float*)d_in[2];
  const float* w_qkv = (const float*)d_in[3];
  const float* w_out = (const float*)d_in[4];
  const float* b_out = (const float*)d_in[5];
  float* out = (float*)d_out;

  char* ws = (char*)d_ws;
  float*  po0   = (float*)(ws + 0);
  float*  po1   = (float*)(ws + 18874368);
  u16*    vsec  = (u16*)(ws + 37748736);
  u16*    qT    = (u16*)(ws + 47185920);
  u16*    kT    = (u16*)(ws + 56623104);
  float*  pl    = (float*)(ws + 66060288);
  float2* stats = (float2*)(ws + 66650112);
  u16*    xnT   = (u16*)(ws + 0);          // aliases po0; dead after gemm1

  gn_stats<<<dim3(B_ * G_), dim3(256), 0, stream>>>(x, stats);
  gn_apply_t<<<dim3(C_ / 64, N_ / 64, B_), dim3(256), 0, stream>>>(x, stats, gamma, beta, xnT);
  gemm_bf16<2><<<dim3(12, 18, B_), dim3(256), 0, stream>>>(
      w_qkv, xnT, nullptr, nullptr, nullptr, nullptr, nullptr, qT, kT, vsec, 1536, N_, C_);
  attn_kernel4<<<dim3(H_, N_ / 128, B_ * SPLIT), dim3(256), 0, stream>>>(qT, kT, vsec, po0, pl);
  gemm_bf16<1><<<dim3(4, 18, B_), dim3(256), 0, stream>>>(
      w_out, nullptr, po0, po1, pl, (void*)out, b_out, nullptr, nullptr, nullptr, C_, N_, C_);
}

// Round 5
// 164.679 us; speedup vs baseline: 1.6283x; 1.1433x over previous
//
#include <hip/hip_runtime.h>
#include <hip/hip_bf16.h>

// SelfAttention fused pipeline, bf16 MFMA path, K-split flash attention.
// x[4,512,48,48] -> GN(32) -> qkv 1x1 conv -> 8-head attn (N=2304,D=64) -> out proj.
//
// ws layout (66.66 MB, < 68.16 MB proven safe):
//   po0  [4][2304][512] f32 @ 0          (first 9.44 MB doubles as xnT before attn)
//   po1  [4][2304][512] f32 @ 18874368
//   v    [4][512][2304] bf16 @ 37748736  (d-major, PV B-operand layout)
//   qT   [4][8][2304][64] bf16 @ 47185920 (QSCALE folded via W_q staging)
//   kT   [4][8][2304][64] bf16 @ 56623104
//   pl   [2][4][8][2304] f32 @ 66060288
//   stats[4][32] float2     @ 66650112
// xnT [4][2304][512] bf16 @ 0 (aliases po0; dead once gemm1 completes)

typedef unsigned short u16;
typedef unsigned int u32;
typedef __attribute__((ext_vector_type(8))) short bf16x8;
typedef __attribute__((ext_vector_type(4))) float f32x4;
typedef __attribute__((ext_vector_type(8))) unsigned short us8;
typedef __attribute__((ext_vector_type(4))) unsigned short us4;

#define B_ 4
#define C_ 512
#define N_ 2304
#define H_ 8
#define D_ 64
#define G_ 32
#define SPLIT 2
#define NT (N_ / 64 / SPLIT)   // 18 k-tiles per split block

// log2(e)/8: folded into W_q at staging so QK^T lands in exp2 domain.
#define QSCALE 0.1803368801111204f
// No max subtraction at all: scores in exp2 domain are ~N(0,1.44), |s|max ~ 12,
// exp2(s) <= ~4096 fits f32/bf16 comfortably; softmax is shift-invariant.

__device__ __forceinline__ u16 f2bf(float f) {
  unsigned u = __float_as_uint(f);
  u += 0x7FFFu + ((u >> 16) & 1u);   // RNE
  return (u16)(u >> 16);
}

__device__ __forceinline__ u32 pack2bf(float lo, float hi) {
  __hip_bfloat162 t = __float22bfloat162_rn(float2{lo, hi});
  u32 r;
  __builtin_memcpy(&r, &t, 4);
  return r;
}

// ---------------- groupnorm stats: one block per (b,g) ----------------
__global__ __launch_bounds__(256) void gn_stats(const float* __restrict__ x,
                                                float2* __restrict__ stats) {
  const int bg = blockIdx.x;
  const float* p = x + (size_t)bg * 16 * N_;
  float s = 0.f, s2 = 0.f;
  for (int i = threadIdx.x; i < 16 * N_ / 4; i += 256) {
    const float4 v = ((const float4*)p)[i];
    s  += v.x + v.y + v.z + v.w;
    s2 += v.x * v.x + v.y * v.y + v.z * v.z + v.w * v.w;
  }
  #pragma unroll
  for (int off = 32; off; off >>= 1) { s += __shfl_down(s, off); s2 += __shfl_down(s2, off); }
  __shared__ float red[8];
  if ((threadIdx.x & 63) == 0) { red[(threadIdx.x >> 6) * 2] = s; red[(threadIdx.x >> 6) * 2 + 1] = s2; }
  __syncthreads();
  if (threadIdx.x == 0) {
    float S = 0.f, S2 = 0.f;
    for (int w = 0; w < 4; w++) { S += red[w * 2]; S2 += red[w * 2 + 1]; }
    const float inv = 1.f / (16.f * N_);
    const float mean = S * inv;
    const float var = S2 * inv - mean * mean;
    stats[bg] = make_float2(mean, rsqrtf(var + 1e-5f));
  }
}

// ---------------- GN apply + transpose -> xnT[b][n][c] bf16 ----------------
__global__ __launch_bounds__(256) void gn_apply_t(
    const float* __restrict__ x, const float2* __restrict__ stats,
    const float* __restrict__ gamma, const float* __restrict__ beta,
    u16* __restrict__ xnT) {
  __shared__ u16 T[64][72];
  const int c0 = blockIdx.x * 64, n0 = blockIdx.y * 64, b = blockIdx.z;
  const int r = threadIdx.x >> 2, ch = (threadIdx.x & 3) * 16;
  const int cc = c0 + r;
  const float2 st = stats[b * G_ + (cc >> 4)];
  const float sc = st.y * gamma[cc];
  const float sh = beta[cc] - st.x * sc;
  const float* src = x + (size_t)(b * C_ + cc) * N_ + n0 + ch;
  #pragma unroll
  for (int j = 0; j < 16; j += 4) {
    const float4 v = *(const float4*)(src + j);
    us4 o; o[0] = f2bf(v.x * sc + sh); o[1] = f2bf(v.y * sc + sh);
    o[2] = f2bf(v.z * sc + sh); o[3] = f2bf(v.w * sc + sh);
    *(us4*)&T[r][ch + j] = o;
  }
  __syncthreads();
  us8 o1, o2;
  #pragma unroll
  for (int j = 0; j < 8; j++) { o1[j] = T[ch + j][r]; o2[j] = T[ch + 8 + j][r]; }
  u16* dst = xnT + (size_t)(b * N_ + n0 + r) * C_ + c0 + ch;
  *(us8*)dst = o1;
  *(us8*)(dst + 8) = o2;
}

// ---------------- GEMM: C[bz][m][n] = A[m][k] * B[bz][n][k]^T ----------------
// A is f32 weights [M][K], cast to bf16 during LDS staging (MODE2: q-rows scaled).
// MODE 2 (qkv): B = xnT bf16; epilogue scatters q->qT, k->kT, v->v (d-major).
// MODE 1 (out proj): B = (po0+po1)*rl normalized at staging; out f32 + bias.
template <int MODE>
__global__ __launch_bounds__(256) void gemm_bf16(
    const float* __restrict__ Af, const u16* __restrict__ Bb16,
    const float* __restrict__ po0, const float* __restrict__ po1,
    const float* __restrict__ pl,
    void* __restrict__ C, const float* __restrict__ bias,
    u16* __restrict__ qT, u16* __restrict__ kT, u16* __restrict__ vout,
    const int M, const int N, const int K) {
  __shared__ u16 As[128][40];
  __shared__ u16 Bs[128][40];
  const int tid = threadIdx.x;
  const int wave = tid >> 6, lane = tid & 63;
  const int l16 = lane & 15, lq = lane >> 4;
  const int m0 = blockIdx.x * 128, n0 = blockIdx.y * 128, bz = blockIdx.z;
  const int wm = (wave >> 1) * 64, wn = (wave & 1) * 64;

  f32x4 acc[4][4];
  #pragma unroll
  for (int mi = 0; mi < 4; mi++)
    #pragma unroll
    for (int ni = 0; ni < 4; ni++) {
      acc[mi][ni][0] = 0.f; acc[mi][ni][1] = 0.f; acc[mi][ni][2] = 0.f; acc[mi][ni][3] = 0.f;
    }

  const int r = tid >> 2, c = (tid & 3) * 8;
  for (int kt = 0; kt < K; kt += 32) {
    __syncthreads();
    // ---- A staging: f32 -> bf16 cast (+QSCALE fold for q rows in MODE2) ----
    #pragma unroll
    for (int half = 0; half < 2; half++) {
      const int row = m0 + r + half * 64;
      const float* ap = Af + (size_t)row * K + kt + c;
      const float4 f0 = *(const float4*)ap;
      const float4 f1 = *(const float4*)(ap + 4);
      const float sc = (MODE == 2 && row < 512) ? QSCALE : 1.0f;
      us8 o;
      o[0] = f2bf(f0.x * sc); o[1] = f2bf(f0.y * sc);
      o[2] = f2bf(f0.z * sc); o[3] = f2bf(f0.w * sc);
      o[4] = f2bf(f1.x * sc); o[5] = f2bf(f1.y * sc);
      o[6] = f2bf(f1.z * sc); o[7] = f2bf(f1.w * sc);
      *(us8*)&As[r + half * 64][c] = o;
    }
    // ---- B staging ----
    if (MODE == 2) {
      const u16* Bb = Bb16 + (size_t)bz * N * K;
      *(us8*)&Bs[r][c]      = *(const us8*)&Bb[(size_t)(n0 + r) * K + kt + c];
      *(us8*)&Bs[r + 64][c] = *(const us8*)&Bb[(size_t)(n0 + r + 64) * K + kt + c];
    } else {
      const int h = (kt + c) >> 6;
      #pragma unroll
      for (int half = 0; half < 2; half++) {
        const int n = n0 + r + half * 64;
        const size_t lidx = ((size_t)(bz * H_) + h) * N_ + n;
        const float rl = 1.0f / (pl[lidx] + pl[lidx + B_ * H_ * N_]);
        const size_t pidx = ((size_t)(bz * N_) + n) * 512 + kt + c;
        const float4 a0 = *(const float4*)&po0[pidx];
        const float4 a1 = *(const float4*)&po0[pidx + 4];
        const float4 b0 = *(const float4*)&po1[pidx];
        const float4 b1 = *(const float4*)&po1[pidx + 4];
        us8 o;
        o[0] = f2bf((a0.x + b0.x) * rl); o[1] = f2bf((a0.y + b0.y) * rl);
        o[2] = f2bf((a0.z + b0.z) * rl); o[3] = f2bf((a0.w + b0.w) * rl);
        o[4] = f2bf((a1.x + b1.x) * rl); o[5] = f2bf((a1.y + b1.y) * rl);
        o[6] = f2bf((a1.z + b1.z) * rl); o[7] = f2bf((a1.w + b1.w) * rl);
        *(us8*)&Bs[r + half * 64][c] = o;
      }
    }
    __syncthreads();
    bf16x8 af[4], bfr[4];
    #pragma unroll
    for (int mi = 0; mi < 4; mi++) af[mi] = *(const bf16x8*)&As[wm + mi * 16 + l16][lq * 8];
    #pragma unroll
    for (int ni = 0; ni < 4; ni++) bfr[ni] = *(const bf16x8*)&Bs[wn + ni * 16 + l16][lq * 8];
    #pragma unroll
    for (int mi = 0; mi < 4; mi++)
      #pragma unroll
      for (int ni = 0; ni < 4; ni++)
        acc[mi][ni] = __builtin_amdgcn_mfma_f32_16x16x32_bf16(af[mi], bfr[ni], acc[mi][ni], 0, 0, 0);
  }
  #pragma unroll
  for (int mi = 0; mi < 4; mi++) {
    const int row0 = m0 + wm + mi * 16 + lq * 4;
    #pragma unroll
    for (int ni = 0; ni < 4; ni++) {
      const int col = n0 + wn + ni * 16 + l16;
      if (MODE == 1) {
        #pragma unroll
        for (int j = 0; j < 4; j++) {
          const size_t idx = ((size_t)bz * M + row0 + j) * N + col;
          ((float*)C)[idx] = acc[mi][ni][j] + bias[row0 + j];
        }
      } else {
        const int which = row0 >> 9;           // 0=q, 1=k, 2=v
        if (which < 2) {
          const int h = (row0 >> 6) & 7, d0 = row0 & 63;
          u16* dst = which ? kT : qT;
          us4 o;
          #pragma unroll
          for (int j = 0; j < 4; j++) o[j] = f2bf(acc[mi][ni][j]);
          *(us4*)&dst[((size_t)((bz * H_ + h) * N_) + col) * D_ + d0] = o;
        } else {
          #pragma unroll
          for (int j = 0; j < 4; j++)
            vout[((size_t)(bz * 512) + (row0 & 511) + j) * N + col] = f2bf(acc[mi][ni][j]);
        }
      }
    }
  }
}

// ---------------- flash attention v5: 8-wave blocks, no-max softmax ----------------
// block = (h, q-tile of 256, b*SPLIT+sp), 8 waves x 32 q-rows, 18 k-tiles.
// S^T = mfma(A=K, B=Q) with a shared zero C-tuple (no per-tile acc init).
// p = exp2(s) raw (no shift); l accumulates in-lane; cvt_pk writes straight
// into the PV a-frag word layout. Partial O (f32) + partial l out; norm in gemm2.
__global__ __launch_bounds__(512) void attn_kernel5(
    const u16* __restrict__ qT, const u16* __restrict__ kT,
    const u16* __restrict__ vsec, float* __restrict__ po0,
    float* __restrict__ pl) {
  __shared__ u16 Ks[2][64][72];
  __shared__ u16 Vs[2][64][72];

  const int h = blockIdx.x;
  const int b = blockIdx.z >> 1, sp = blockIdx.z & 1;
  const int q0 = blockIdx.y * 256;
  const int tid = threadIdx.x;
  const int wave = tid >> 6, lane = tid & 63;
  const int l16 = lane & 15, lq = lane >> 4;
  const int kt0 = sp * NT;

  bf16x8 qf[2][2];
  {
    const u16* qb = qT + ((size_t)((b * H_ + h) * N_ + q0 + wave * 32)) * D_;
    #pragma unroll
    for (int qi = 0; qi < 2; qi++)
      #pragma unroll
      for (int dh = 0; dh < 2; dh++)
        qf[qi][dh] = *(const bf16x8*)(qb + (size_t)(qi * 16 + l16) * D_ + dh * 32 + lq * 8);
  }

  float l[2] = {0.f, 0.f};
  f32x4 acc[2][4];
  #pragma unroll
  for (int qi = 0; qi < 2; qi++)
    #pragma unroll
    for (int di = 0; di < 4; di++) {
      acc[qi][di][0] = 0.f; acc[qi][di][1] = 0.f; acc[qi][di][2] = 0.f; acc[qi][di][3] = 0.f;
    }
  const f32x4 z4 = {0.f, 0.f, 0.f, 0.f};   // shared C-input for first QK MFMA

  const u16* kbase = kT + (size_t)(b * H_ + h) * N_ * D_;
  const u16* vbase = vsec + ((size_t)(b * 512) + h * D_) * N_;
  // 512 threads stage 64x64 K + 64x64 V: one us8 of each per thread.
  const int sr = tid >> 3, sc = (tid & 7) * 8;
  // permuted V columns so PV b-frag is one b128 read (perm(c+4) == perm(c)+8)
  const int cb = sc & 31;
  const int colp = (sc & ~31) + ((cb >> 2) & 3) * 8 + ((cb >> 4) & 1) * 4;

  // prologue: stage tile kt0
  {
    *(us8*)&Ks[0][sr][sc] = *(const us8*)&kbase[(size_t)(kt0 * 64 + sr) * D_ + sc];
    us8 v0 = *(const us8*)&vbase[(size_t)sr * N_ + kt0 * 64 + sc];
    *(us4*)&Vs[0][sr][colp]     = ((us4*)&v0)[0];
    *(us4*)&Vs[0][sr][colp + 8] = ((us4*)&v0)[1];
  }

  int cur = 0;
  for (int t = 0; t < NT; t++) {
    const int kt = kt0 + t;
    __syncthreads();

    us8 nk0, nv0;
    const bool more = (t + 1 < NT);
    if (more) {
      nk0 = *(const us8*)&kbase[(size_t)((kt + 1) * 64 + sr) * D_ + sc];
      nv0 = *(const us8*)&vbase[(size_t)sr * N_ + (kt + 1) * 64 + sc];
    }

    // ---- S^T = K Q^T (C-in = shared zero tuple; no per-tile init) ----
    f32x4 s[2][4];
    __builtin_amdgcn_s_setprio(1);
    #pragma unroll
    for (int ni = 0; ni < 4; ni++) {
      const bf16x8 k0 = *(const bf16x8*)&Ks[cur][ni * 16 + l16][lq * 8];
      const bf16x8 k1 = *(const bf16x8*)&Ks[cur][ni * 16 + l16][32 + lq * 8];
      #pragma unroll
      for (int qi = 0; qi < 2; qi++) {
        s[qi][ni] = __builtin_amdgcn_mfma_f32_16x16x32_bf16(k0, qf[qi][0], z4, 0, 0, 0);
        s[qi][ni] = __builtin_amdgcn_mfma_f32_16x16x32_bf16(k1, qf[qi][1], s[qi][ni], 0, 0, 0);
      }
    }
    __builtin_amdgcn_s_setprio(0);

    // ---- p = exp2(s); l in-lane; pack directly into PV a-frag words ----
    union { u32 w[4]; bf16x8 v; } af[2][2];   // [qi][kh]
    #pragma unroll
    for (int qi = 0; qi < 2; qi++) {
      float rs = 0.f;
      #pragma unroll
      for (int ni = 0; ni < 4; ni++) {
        const float p0 = __builtin_amdgcn_exp2f(s[qi][ni][0]);
        const float p1 = __builtin_amdgcn_exp2f(s[qi][ni][1]);
        const float p2 = __builtin_amdgcn_exp2f(s[qi][ni][2]);
        const float p3 = __builtin_amdgcn_exp2f(s[qi][ni][3]);
        rs += (p0 + p1) + (p2 + p3);
        af[qi][ni >> 1].w[(ni & 1) * 2]     = pack2bf(p0, p1);
        af[qi][ni >> 1].w[(ni & 1) * 2 + 1] = pack2bf(p2, p3);
      }
      l[qi] += rs;
    }

    // ---- PV ----
    __builtin_amdgcn_s_setprio(1);
    #pragma unroll
    for (int kh = 0; kh < 2; kh++) {
      #pragma unroll
      for (int di = 0; di < 4; di++) {
        const bf16x8 vf = *(const bf16x8*)&Vs[cur][di * 16 + l16][kh * 32 + lq * 8];
        #pragma unroll
        for (int qi = 0; qi < 2; qi++)
          acc[qi][di] = __builtin_amdgcn_mfma_f32_16x16x32_bf16(af[qi][kh].v, vf, acc[qi][di], 0, 0, 0);
      }
    }
    __builtin_amdgcn_s_setprio(0);

    if (more) {
      *(us8*)&Ks[cur ^ 1][sr][sc] = nk0;
      *(us4*)&Vs[cur ^ 1][sr][colp]     = ((us4*)&nv0)[0];
      *(us4*)&Vs[cur ^ 1][sr][colp + 8] = ((us4*)&nv0)[1];
    }
    cur ^= 1;
  }

  // ---- epilogue: write unnormalized partial O (f32) + partial l ----
  float* po = po0 + (size_t)sp * (B_ * N_ * 512);
  #pragma unroll
  for (int qi = 0; qi < 2; qi++) {
    l[qi] += __shfl_xor(l[qi], 16);
    l[qi] += __shfl_xor(l[qi], 32);
  }
  if (lq == 0) {
    #pragma unroll
    for (int qi = 0; qi < 2; qi++) {
      const int n = q0 + wave * 32 + qi * 16 + l16;
      pl[((size_t)((sp * B_ + b) * H_) + h) * N_ + n] = l[qi];
    }
  }
  #pragma unroll
  for (int qi = 0; qi < 2; qi++)
    #pragma unroll
    for (int di = 0; di < 4; di++)
      #pragma unroll
      for (int j = 0; j < 4; j++) {
        const int n = q0 + wave * 32 + qi * 16 + lq * 4 + j;
        po[((size_t)(b * N_) + n) * 512 + h * D_ + di * 16 + l16] = acc[qi][di][j];
      }
}

extern "C" void kernel_launch(void* const* d_in, const int* in_sizes, int n_in,
                              void* d_out, int out_size, void* d_ws, size_t ws_size,
                              hipStream_t stream) {
  const float* x     = (const float*)d_in[0];
  const float* gamma = (const float*)d_in[1];
  const float* beta  = (const float*)d_in[2];
  const float* w_qkv = (const float*)d_in[3];
  const float* w_out = (const float*)d_in[4];
  const float* b_out = (const float*)d_in[5];
  float* out = (float*)d_out;

  char* ws = (char*)d_ws;
  float*  po0   = (float*)(ws + 0);
  float*  po1   = (float*)(ws + 18874368);
  u16*    vsec  = (u16*)(ws + 37748736);
  u16*    qT    = (u16*)(ws + 47185920);
  u16*    kT    = (u16*)(ws + 56623104);
  float*  pl    = (float*)(ws + 66060288);
  float2* stats = (float2*)(ws + 66650112);
  u16*    xnT   = (u16*)(ws + 0);          // aliases po0; dead after gemm1

  gn_stats<<<dim3(B_ * G_), dim3(256), 0, stream>>>(x, stats);
  gn_apply_t<<<dim3(C_ / 64, N_ / 64, B_), dim3(256), 0, stream>>>(x, stats, gamma, beta, xnT);
  gemm_bf16<2><<<dim3(12, 18, B_), dim3(256), 0, stream>>>(
      w_qkv, xnT, nullptr, nullptr, nullptr, nullptr, nullptr, qT, kT, vsec, 1536, N_, C_);
  attn_kernel5<<<dim3(H_, N_ / 256, B_ * SPLIT), dim3(512), 0, stream>>>(qT, kT, vsec, po0, pl);
  gemm_bf16<1><<<dim3(4, 18, B_), dim3(256), 0, stream>>>(
      w_out, nullptr, po0, po1, pl, (void*)out, b_out, nullptr, nullptr, nullptr, C_, N_, C_);
}

// Round 6
// 164.168 us; speedup vs baseline: 1.6334x; 1.0031x over previous
//
#include <hip/hip_runtime.h>
#include <hip/hip_bf16.h>

// SelfAttention fused pipeline, bf16 MFMA path, K-split flash attention.
// x[4,512,48,48] -> GN(32) -> qkv 1x1 conv -> 8-head attn (N=2304,D=64) -> out proj.
//
// ws layout (66.66 MB):
//   po0  [4][2304][512] f32 @ 0          (first 9.44 MB doubles as xnT before attn)
//   po1  [4][2304][512] f32 @ 18874368
//   v    [4][512][2304] bf16 @ 37748736  (d-major; REUSED as innerT bf16 after attn)
//   qT   [4][8][2304][64] bf16 @ 47185920 (QSCALE folded via W_q staging)
//   kT   [4][8][2304][64] bf16 @ 56623104
//   pl   [2][4][8][2304] f32 @ 66060288
//   stats[4][32] float2     @ 66650112

typedef unsigned short u16;
typedef unsigned int u32;
typedef __attribute__((ext_vector_type(8))) short bf16x8;
typedef __attribute__((ext_vector_type(4))) float f32x4;
typedef __attribute__((ext_vector_type(8))) unsigned short us8;
typedef __attribute__((ext_vector_type(4))) unsigned short us4;

#define B_ 4
#define C_ 512
#define N_ 2304
#define H_ 8
#define D_ 64
#define G_ 32
#define SPLIT 2
#define NT (N_ / 64 / SPLIT)   // 18 k-tiles per split block

// log2(e)/8: folded into W_q at staging so QK^T lands in exp2 domain.
#define QSCALE 0.1803368801111204f
// No max subtraction: exp2-domain scores |s| <~ 12, exp2(s) <= ~4096 fits
// f32/bf16 comfortably; softmax is shift-invariant.

__device__ __forceinline__ u16 f2bf(float f) {
  unsigned u = __float_as_uint(f);
  u += 0x7FFFu + ((u >> 16) & 1u);   // RNE
  return (u16)(u >> 16);
}

__device__ __forceinline__ u32 pack2bf(float lo, float hi) {
  __hip_bfloat162 t = __float22bfloat162_rn(float2{lo, hi});
  u32 r;
  __builtin_memcpy(&r, &t, 4);
  return r;
}

// ---------------- groupnorm stats: one block per (b,g) ----------------
__global__ __launch_bounds__(256) void gn_stats(const float* __restrict__ x,
                                                float2* __restrict__ stats) {
  const int bg = blockIdx.x;
  const float* p = x + (size_t)bg * 16 * N_;
  float s = 0.f, s2 = 0.f;
  for (int i = threadIdx.x; i < 16 * N_ / 4; i += 256) {
    const float4 v = ((const float4*)p)[i];
    s  += v.x + v.y + v.z + v.w;
    s2 += v.x * v.x + v.y * v.y + v.z * v.z + v.w * v.w;
  }
  #pragma unroll
  for (int off = 32; off; off >>= 1) { s += __shfl_down(s, off); s2 += __shfl_down(s2, off); }
  __shared__ float red[8];
  if ((threadIdx.x & 63) == 0) { red[(threadIdx.x >> 6) * 2] = s; red[(threadIdx.x >> 6) * 2 + 1] = s2; }
  __syncthreads();
  if (threadIdx.x == 0) {
    float S = 0.f, S2 = 0.f;
    for (int w = 0; w < 4; w++) { S += red[w * 2]; S2 += red[w * 2 + 1]; }
    const float inv = 1.f / (16.f * N_);
    const float mean = S * inv;
    const float var = S2 * inv - mean * mean;
    stats[bg] = make_float2(mean, rsqrtf(var + 1e-5f));
  }
}

// ---------------- GN apply + transpose -> xnT[b][n][c] bf16 ----------------
__global__ __launch_bounds__(256) void gn_apply_t(
    const float* __restrict__ x, const float2* __restrict__ stats,
    const float* __restrict__ gamma, const float* __restrict__ beta,
    u16* __restrict__ xnT) {
  __shared__ u16 T[64][72];
  const int c0 = blockIdx.x * 64, n0 = blockIdx.y * 64, b = blockIdx.z;
  const int r = threadIdx.x >> 2, ch = (threadIdx.x & 3) * 16;
  const int cc = c0 + r;
  const float2 st = stats[b * G_ + (cc >> 4)];
  const float sc = st.y * gamma[cc];
  const float sh = beta[cc] - st.x * sc;
  const float* src = x + (size_t)(b * C_ + cc) * N_ + n0 + ch;
  #pragma unroll
  for (int j = 0; j < 16; j += 4) {
    const float4 v = *(const float4*)(src + j);
    us4 o; o[0] = f2bf(v.x * sc + sh); o[1] = f2bf(v.y * sc + sh);
    o[2] = f2bf(v.z * sc + sh); o[3] = f2bf(v.w * sc + sh);
    *(us4*)&T[r][ch + j] = o;
  }
  __syncthreads();
  us8 o1, o2;
  #pragma unroll
  for (int j = 0; j < 8; j++) { o1[j] = T[ch + j][r]; o2[j] = T[ch + 8 + j][r]; }
  u16* dst = xnT + (size_t)(b * N_ + n0 + r) * C_ + c0 + ch;
  *(us8*)dst = o1;
  *(us8*)(dst + 8) = o2;
}

// ---------------- GEMM: C[bz][m][n] = A[m][k] * B[bz][n][k]^T ----------------
// A: f32 weights [M][K], cast to bf16 during LDS staging (MODE2 q-rows scaled).
// B: bf16 [bz][N][K] (K contiguous) for both modes.
// MODE 2 (qkv): epilogue scatters q->qT, k->kT (both [b][h][n][d]), v->vout (d-major).
// MODE 1 (out proj): f32 output + bias.
template <int MODE>
__global__ __launch_bounds__(256) void gemm_bf16(
    const float* __restrict__ Af, const u16* __restrict__ Bb16,
    void* __restrict__ C, const float* __restrict__ bias,
    u16* __restrict__ qT, u16* __restrict__ kT, u16* __restrict__ vout,
    const int M, const int N, const int K) {
  __shared__ u16 As[128][40];
  __shared__ u16 Bs[128][40];
  const int tid = threadIdx.x;
  const int wave = tid >> 6, lane = tid & 63;
  const int l16 = lane & 15, lq = lane >> 4;
  const int m0 = blockIdx.x * 128, n0 = blockIdx.y * 128, bz = blockIdx.z;
  const int wm = (wave >> 1) * 64, wn = (wave & 1) * 64;
  const u16* Bb = Bb16 + (size_t)bz * N * K;

  f32x4 acc[4][4];
  #pragma unroll
  for (int mi = 0; mi < 4; mi++)
    #pragma unroll
    for (int ni = 0; ni < 4; ni++) {
      acc[mi][ni][0] = 0.f; acc[mi][ni][1] = 0.f; acc[mi][ni][2] = 0.f; acc[mi][ni][3] = 0.f;
    }

  const int r = tid >> 2, c = (tid & 3) * 8;
  for (int kt = 0; kt < K; kt += 32) {
    __syncthreads();
    // A staging: f32 -> bf16 cast (+QSCALE fold for q rows in MODE2)
    #pragma unroll
    for (int half = 0; half < 2; half++) {
      const int row = m0 + r + half * 64;
      const float* ap = Af + (size_t)row * K + kt + c;
      const float4 f0 = *(const float4*)ap;
      const float4 f1 = *(const float4*)(ap + 4);
      const float sc = (MODE == 2 && row < 512) ? QSCALE : 1.0f;
      us8 o;
      o[0] = f2bf(f0.x * sc); o[1] = f2bf(f0.y * sc);
      o[2] = f2bf(f0.z * sc); o[3] = f2bf(f0.w * sc);
      o[4] = f2bf(f1.x * sc); o[5] = f2bf(f1.y * sc);
      o[6] = f2bf(f1.z * sc); o[7] = f2bf(f1.w * sc);
      *(us8*)&As[r + half * 64][c] = o;
    }
    *(us8*)&Bs[r][c]      = *(const us8*)&Bb[(size_t)(n0 + r) * K + kt + c];
    *(us8*)&Bs[r + 64][c] = *(const us8*)&Bb[(size_t)(n0 + r + 64) * K + kt + c];
    __syncthreads();
    bf16x8 af[4], bfr[4];
    #pragma unroll
    for (int mi = 0; mi < 4; mi++) af[mi] = *(const bf16x8*)&As[wm + mi * 16 + l16][lq * 8];
    #pragma unroll
    for (int ni = 0; ni < 4; ni++) bfr[ni] = *(const bf16x8*)&Bs[wn + ni * 16 + l16][lq * 8];
    #pragma unroll
    for (int mi = 0; mi < 4; mi++)
      #pragma unroll
      for (int ni = 0; ni < 4; ni++)
        acc[mi][ni] = __builtin_amdgcn_mfma_f32_16x16x32_bf16(af[mi], bfr[ni], acc[mi][ni], 0, 0, 0);
  }
  #pragma unroll
  for (int mi = 0; mi < 4; mi++) {
    const int row0 = m0 + wm + mi * 16 + lq * 4;
    #pragma unroll
    for (int ni = 0; ni < 4; ni++) {
      const int col = n0 + wn + ni * 16 + l16;
      if (MODE == 1) {
        #pragma unroll
        for (int j = 0; j < 4; j++) {
          const size_t idx = ((size_t)bz * M + row0 + j) * N + col;
          ((float*)C)[idx] = acc[mi][ni][j] + bias[row0 + j];
        }
      } else {
        const int which = row0 >> 9;           // 0=q, 1=k, 2=v
        if (which < 2) {
          const int h = (row0 >> 6) & 7, d0 = row0 & 63;
          u16* dst = which ? kT : qT;
          us4 o;
          #pragma unroll
          for (int j = 0; j < 4; j++) o[j] = f2bf(acc[mi][ni][j]);
          *(us4*)&dst[((size_t)((bz * H_ + h) * N_) + col) * D_ + d0] = o;
        } else {
          #pragma unroll
          for (int j = 0; j < 4; j++)
            vout[((size_t)(bz * 512) + (row0 & 511) + j) * N + col] = f2bf(acc[mi][ni][j]);
        }
      }
    }
  }
}

// ---------------- flash attention v6: prefetch distance 2 (counted vmcnt) ----------------
// block = (h, q-tile of 256, b*SPLIT+sp), 8 waves x 32 q-rows, 18 k-tiles.
// Hand-unrolled by 2 with static reg sets (ka/va, kb/vb) so the LDS write of
// tile t+1 waits on a COUNTED vmcnt (tile t+2's loads stay in flight).
__global__ __launch_bounds__(512) void attn_kernel6(
    const u16* __restrict__ qT, const u16* __restrict__ kT,
    const u16* __restrict__ vsec, float* __restrict__ po0,
    float* __restrict__ pl) {
  __shared__ u16 Ks[2][64][72];
  __shared__ u16 Vs[2][64][72];

  const int h = blockIdx.x;
  const int b = blockIdx.z >> 1, sp = blockIdx.z & 1;
  const int q0 = blockIdx.y * 256;
  const int tid = threadIdx.x;
  const int wave = tid >> 6, lane = tid & 63;
  const int l16 = lane & 15, lq = lane >> 4;
  const int kt0 = sp * NT;

  bf16x8 qf[2][2];
  {
    const u16* qb = qT + ((size_t)((b * H_ + h) * N_ + q0 + wave * 32)) * D_;
    #pragma unroll
    for (int qi = 0; qi < 2; qi++)
      #pragma unroll
      for (int dh = 0; dh < 2; dh++)
        qf[qi][dh] = *(const bf16x8*)(qb + (size_t)(qi * 16 + l16) * D_ + dh * 32 + lq * 8);
  }

  float l[2] = {0.f, 0.f};
  f32x4 acc[2][4];
  #pragma unroll
  for (int qi = 0; qi < 2; qi++)
    #pragma unroll
    for (int di = 0; di < 4; di++) {
      acc[qi][di][0] = 0.f; acc[qi][di][1] = 0.f; acc[qi][di][2] = 0.f; acc[qi][di][3] = 0.f;
    }
  const f32x4 z4 = {0.f, 0.f, 0.f, 0.f};

  const u16* kbase = kT + (size_t)(b * H_ + h) * N_ * D_;
  const u16* vbase = vsec + ((size_t)(b * 512) + h * D_) * N_;
  const int sr = tid >> 3, sc = (tid & 7) * 8;
  // permuted V columns so PV b-frag is one b128 read
  const int cb = sc & 31;
  const int colp = (sc & ~31) + ((cb >> 2) & 3) * 8 + ((cb >> 4) & 1) * 4;

  // one tile's compute: QK^T (swapped) -> exp2 -> PV, all on LDS buffer `buf`
  auto ATTN_TILE = [&](const int buf) {
    f32x4 s[2][4];
    __builtin_amdgcn_s_setprio(1);
    #pragma unroll
    for (int ni = 0; ni < 4; ni++) {
      const bf16x8 k0 = *(const bf16x8*)&Ks[buf][ni * 16 + l16][lq * 8];
      const bf16x8 k1 = *(const bf16x8*)&Ks[buf][ni * 16 + l16][32 + lq * 8];
      #pragma unroll
      for (int qi = 0; qi < 2; qi++) {
        s[qi][ni] = __builtin_amdgcn_mfma_f32_16x16x32_bf16(k0, qf[qi][0], z4, 0, 0, 0);
        s[qi][ni] = __builtin_amdgcn_mfma_f32_16x16x32_bf16(k1, qf[qi][1], s[qi][ni], 0, 0, 0);
      }
    }
    __builtin_amdgcn_s_setprio(0);
    union { u32 w[4]; bf16x8 v; } af[2][2];   // [qi][kh]
    #pragma unroll
    for (int qi = 0; qi < 2; qi++) {
      float rs = 0.f;
      #pragma unroll
      for (int ni = 0; ni < 4; ni++) {
        const float p0 = __builtin_amdgcn_exp2f(s[qi][ni][0]);
        const float p1 = __builtin_amdgcn_exp2f(s[qi][ni][1]);
        const float p2 = __builtin_amdgcn_exp2f(s[qi][ni][2]);
        const float p3 = __builtin_amdgcn_exp2f(s[qi][ni][3]);
        rs += (p0 + p1) + (p2 + p3);
        af[qi][ni >> 1].w[(ni & 1) * 2]     = pack2bf(p0, p1);
        af[qi][ni >> 1].w[(ni & 1) * 2 + 1] = pack2bf(p2, p3);
      }
      l[qi] += rs;
    }
    __builtin_amdgcn_s_setprio(1);
    #pragma unroll
    for (int kh = 0; kh < 2; kh++)
      #pragma unroll
      for (int di = 0; di < 4; di++) {
        const bf16x8 vf = *(const bf16x8*)&Vs[buf][di * 16 + l16][kh * 32 + lq * 8];
        #pragma unroll
        for (int qi = 0; qi < 2; qi++)
          acc[qi][di] = __builtin_amdgcn_mfma_f32_16x16x32_bf16(af[qi][kh].v, vf, acc[qi][di], 0, 0, 0);
      }
    __builtin_amdgcn_s_setprio(0);
  };

  // prologue: tile kt0 direct to LDS[0]; issue loads for kt0+1, kt0+2
  {
    *(us8*)&Ks[0][sr][sc] = *(const us8*)&kbase[(size_t)(kt0 * 64 + sr) * D_ + sc];
    us8 v0 = *(const us8*)&vbase[(size_t)sr * N_ + kt0 * 64 + sc];
    *(us4*)&Vs[0][sr][colp]     = ((us4*)&v0)[0];
    *(us4*)&Vs[0][sr][colp + 8] = ((us4*)&v0)[1];
  }
  us8 ka = *(const us8*)&kbase[(size_t)((kt0 + 1) * 64 + sr) * D_ + sc];
  us8 va = *(const us8*)&vbase[(size_t)sr * N_ + (kt0 + 1) * 64 + sc];
  us8 kb = *(const us8*)&kbase[(size_t)((kt0 + 2) * 64 + sr) * D_ + sc];
  us8 vb = *(const us8*)&vbase[(size_t)sr * N_ + (kt0 + 2) * 64 + sc];

  for (int t = 0; t < NT; t += 2) {
    __syncthreads();
    ATTN_TILE(0);                              // tile t (LDS[0])
    // write tile t+1 (set A) -> LDS[1]; counted vmcnt (set B stays in flight)
    *(us8*)&Ks[1][sr][sc] = ka;
    *(us4*)&Vs[1][sr][colp]     = ((us4*)&va)[0];
    *(us4*)&Vs[1][sr][colp + 8] = ((us4*)&va)[1];
    {
      const int u = kt0 + ((t + 3 < NT) ? t + 3 : NT - 1);
      ka = *(const us8*)&kbase[(size_t)(u * 64 + sr) * D_ + sc];
      va = *(const us8*)&vbase[(size_t)sr * N_ + u * 64 + sc];
    }
    __syncthreads();
    ATTN_TILE(1);                              // tile t+1 (LDS[1])
    *(us8*)&Ks[0][sr][sc] = kb;
    *(us4*)&Vs[0][sr][colp]     = ((us4*)&vb)[0];
    *(us4*)&Vs[0][sr][colp + 8] = ((us4*)&vb)[1];
    {
      const int u = kt0 + ((t + 4 < NT) ? t + 4 : NT - 1);
      kb = *(const us8*)&kbase[(size_t)(u * 64 + sr) * D_ + sc];
      vb = *(const us8*)&vbase[(size_t)sr * N_ + u * 64 + sc];
    }
  }

  // ---- epilogue: write unnormalized partial O (f32) + partial l ----
  float* po = po0 + (size_t)sp * (B_ * N_ * 512);
  #pragma unroll
  for (int qi = 0; qi < 2; qi++) {
    l[qi] += __shfl_xor(l[qi], 16);
    l[qi] += __shfl_xor(l[qi], 32);
  }
  if (lq == 0) {
    #pragma unroll
    for (int qi = 0; qi < 2; qi++) {
      const int n = q0 + wave * 32 + qi * 16 + l16;
      pl[((size_t)((sp * B_ + b) * H_) + h) * N_ + n] = l[qi];
    }
  }
  #pragma unroll
  for (int qi = 0; qi < 2; qi++)
    #pragma unroll
    for (int di = 0; di < 4; di++)
      #pragma unroll
      for (int j = 0; j < 4; j++) {
        const int n = q0 + wave * 32 + qi * 16 + lq * 4 + j;
        po[((size_t)(b * N_) + n) * 512 + h * D_ + di * 16 + l16] = acc[qi][di][j];
      }
}

// ---------------- combine: innerT = (po0+po1) * 1/(pl0+pl1), bf16 ----------------
// block = 4 rows of (b,n); 64 lanes x 8 channels each.
__global__ __launch_bounds__(256) void combine_norm(
    const float* __restrict__ po0, const float* __restrict__ po1,
    const float* __restrict__ pl, u16* __restrict__ innerT) {
  const int bn = blockIdx.x * 4 + (threadIdx.x >> 6);   // b*N + n
  const int b = bn / N_, n = bn - b * N_;
  const int c0 = (threadIdx.x & 63) * 8;
  const int h = c0 >> 6;
  const size_t lidx = ((size_t)(b * H_) + h) * N_ + n;
  const float rl = 1.0f / (pl[lidx] + pl[lidx + (size_t)B_ * H_ * N_]);
  const size_t base = (size_t)bn * 512 + c0;
  const float4 a0 = *(const float4*)&po0[base];
  const float4 a1 = *(const float4*)&po0[base + 4];
  const float4 b0 = *(const float4*)&po1[base];
  const float4 b1 = *(const float4*)&po1[base + 4];
  us8 o;
  o[0] = f2bf((a0.x + b0.x) * rl); o[1] = f2bf((a0.y + b0.y) * rl);
  o[2] = f2bf((a0.z + b0.z) * rl); o[3] = f2bf((a0.w + b0.w) * rl);
  o[4] = f2bf((a1.x + b1.x) * rl); o[5] = f2bf((a1.y + b1.y) * rl);
  o[6] = f2bf((a1.z + b1.z) * rl); o[7] = f2bf((a1.w + b1.w) * rl);
  *(us8*)&innerT[base] = o;
}

extern "C" void kernel_launch(void* const* d_in, const int* in_sizes, int n_in,
                              void* d_out, int out_size, void* d_ws, size_t ws_size,
                              hipStream_t stream) {
  const float* x     = (const float*)d_in[0];
  const float* gamma = (const float*)d_in[1];
  const float* beta  = (const float*)d_in[2];
  const float* w_qkv = (const float*)d_in[3];
  const float* w_out = (const float*)d_in[4];
  const float* b_out = (const float*)d_in[5];
  float* out = (float*)d_out;

  char* ws = (char*)d_ws;
  float*  po0    = (float*)(ws + 0);
  float*  po1    = (float*)(ws + 18874368);
  u16*    vsec   = (u16*)(ws + 37748736);
  u16*    qT     = (u16*)(ws + 47185920);
  u16*    kT     = (u16*)(ws + 56623104);
  float*  pl     = (float*)(ws + 66060288);
  float2* stats  = (float2*)(ws + 66650112);
  u16*    xnT    = (u16*)(ws + 0);          // aliases po0; dead after gemm1
  u16*    innerT = vsec;                    // aliases vsec; vsec dead after attn

  gn_stats<<<dim3(B_ * G_), dim3(256), 0, stream>>>(x, stats);
  gn_apply_t<<<dim3(C_ / 64, N_ / 64, B_), dim3(256), 0, stream>>>(x, stats, gamma, beta, xnT);
  gemm_bf16<2><<<dim3(12, 18, B_), dim3(256), 0, stream>>>(
      w_qkv, xnT, nullptr, nullptr, qT, kT, vsec, 1536, N_, C_);
  attn_kernel6<<<dim3(H_, N_ / 256, B_ * SPLIT), dim3(512), 0, stream>>>(qT, kT, vsec, po0, pl);
  combine_norm<<<dim3(B_ * N_ / 4), dim3(256), 0, stream>>>(po0, po1, pl, innerT);
  gemm_bf16<1><<<dim3(4, 18, B_), dim3(256), 0, stream>>>(
      w_out, innerT, (void*)out, b_out, nullptr, nullptr, nullptr, C_, N_, C_);
}